// Round 5
// baseline (830.712 us; speedup 1.0000x reference)
//
#include <hip/hip_runtime.h>
#include <hip/hip_bf16.h>
#include <math.h>

#define B_   2
#define S_   2048
#define D_   1024
#define H_   16
#define HD_  64
#define DFF_ 4096
#define M_   (B_*S_)   // 4096 rows
#define SCALE_ 0.08838834764831845f  // 1/sqrt(128)

typedef __attribute__((ext_vector_type(8))) short bf16x8;
typedef __attribute__((ext_vector_type(4))) float f32x4;

#define MFMA16(a,b,c) __builtin_amdgcn_mfma_f32_16x16x32_bf16((a),(b),(c),0,0,0)

__device__ __forceinline__ unsigned short f2b(float f) {
    union { float f; unsigned u; } v; v.f = f;
    return (unsigned short)((v.u + 0x7FFFu + ((v.u >> 16) & 1u)) >> 16);
}
__device__ __forceinline__ float softplus_f(float x) {
    return fmaxf(x, 0.f) + log1pf(__expf(-fabsf(x)));
}
// async global->LDS, 16B per lane. LDS dest = base + lane*16 (wave-uniform base).
__device__ __forceinline__ void g2l16(const void* g, void* l) {
    __builtin_amdgcn_global_load_lds(
        (const __attribute__((address_space(1))) unsigned int*)g,
        (__attribute__((address_space(3))) unsigned int*)l, 16, 0, 0);
}

// ---------------------------------------------------------------------------
__global__ __launch_bounds__(256) void conv_bf16_kernel(
    const float* __restrict__ in, unsigned short* __restrict__ out)
{
    int i = blockIdx.x * 256 + threadIdx.x;
    out[i] = f2b(in[i]);
}

// ---------------------------------------------------------------------------
// Weight transpose + bf16: W[K][N] fp32 -> WT[N][K] bf16
// ---------------------------------------------------------------------------
__global__ __launch_bounds__(256) void wtrans_kernel(
    const float* __restrict__ W, unsigned short* __restrict__ WT, int K, int N)
{
    __shared__ float tile[32][33];
    const int n0 = blockIdx.x * 32, k0 = blockIdx.y * 32;
    const int tx = threadIdx.x & 31, ty = threadIdx.x >> 5;  // ty 0..7
    #pragma unroll
    for (int i = 0; i < 4; i++)
        tile[ty + 8*i][tx] = W[(size_t)(k0 + ty + 8*i) * N + n0 + tx];
    __syncthreads();
    #pragma unroll
    for (int i = 0; i < 4; i++)
        WT[(size_t)(n0 + ty + 8*i) * K + k0 + tx] = f2b(tile[tx][ty + 8*i]);
}

// ---------------------------------------------------------------------------
__global__ __launch_bounds__(256) void bcat_kernel(
    const float* __restrict__ a, const float* __restrict__ b,
    const float* __restrict__ c, float* __restrict__ o)
{
    int i = blockIdx.x * 256 + threadIdx.x;
    o[i] = (i < 1024) ? a[i] : (i < 2048 ? b[i - 1024] : c[i - 2048]);
}

// ---------------------------------------------------------------------------
// Generic m97-style bf16 GEMM with optional split-K (gridDim.z slices).
// C[M,N] = A[M,(lda)] @ WT[N,(lda)]^T (+bias on z=0), opt relu.
// 128x128 tile, BK=32, staging via global_load_lds width=16.
// z-slice k-range: [z*Kslice, (z+1)*Kslice); outF has M*N floats per slice.
// ---------------------------------------------------------------------------
__global__ __launch_bounds__(256) void gemm_bf16_kernel(
    const unsigned short* __restrict__ A,
    const unsigned short* __restrict__ WT,
    const float* __restrict__ bias,
    float* __restrict__ outF, unsigned short* __restrict__ outB,
    int M, int Kslice, int lda, int N, int relu)
{
    __shared__ unsigned short As[128 * 32];
    __shared__ unsigned short Bs[128 * 32];

    const int tid = threadIdx.x;
    const int w = tid >> 6, lane = tid & 63;
    const int quad = lane >> 4, l16 = lane & 15;
    const size_t m0 = (size_t)blockIdx.y * 128, n0 = (size_t)blockIdx.x * 128;
    const int wm = (w >> 1) * 64, wn = (w & 1) * 64;
    const int koff = blockIdx.z * Kslice;

    const int srow = w * 32 + (lane >> 2);
    const int schunk = (lane & 3) * 8;
    const unsigned short* ga = A  + (m0 + srow) * lda + koff + schunk;
    const unsigned short* gb = WT + (n0 + srow) * lda + koff + schunk;
    unsigned short* lA0 = &As[(w * 32) * 32];
    unsigned short* lA1 = &As[(w * 32 + 16) * 32];
    unsigned short* lB0 = &Bs[(w * 32) * 32];
    unsigned short* lB1 = &Bs[(w * 32 + 16) * 32];
    const size_t K16 = (size_t)16 * lda;

    f32x4 acc[4][4] = {};

    for (int k0 = 0; k0 < Kslice; k0 += 32) {
        g2l16(ga + k0,       lA0);
        g2l16(ga + K16 + k0, lA1);
        g2l16(gb + k0,       lB0);
        g2l16(gb + K16 + k0, lB1);
        __syncthreads();

        bf16x8 af[4], bfr[4];
        #pragma unroll
        for (int t = 0; t < 4; t++) {
            af[t]  = *(const bf16x8*)&As[(wm + t * 16 + l16) * 32 + quad * 8];
            bfr[t] = *(const bf16x8*)&Bs[(wn + t * 16 + l16) * 32 + quad * 8];
        }
        #pragma unroll
        for (int mt = 0; mt < 4; mt++)
            #pragma unroll
            for (int nt = 0; nt < 4; nt++)
                acc[mt][nt] = MFMA16(af[mt], bfr[nt], acc[mt][nt]);
        __syncthreads();
    }

    float bv[4];
    #pragma unroll
    for (int nt = 0; nt < 4; nt++)
        bv[nt] = (blockIdx.z == 0) ? bias[n0 + wn + nt * 16 + l16] : 0.f;

    float* outFz = outF ? outF + (size_t)blockIdx.z * M * N : nullptr;

    #pragma unroll
    for (int mt = 0; mt < 4; mt++) {
        #pragma unroll
        for (int nt = 0; nt < 4; nt++) {
            const size_t n = n0 + wn + nt * 16 + l16;
            #pragma unroll
            for (int r = 0; r < 4; r++) {
                const size_t m = m0 + wm + mt * 16 + quad * 4 + r;
                float val = acc[mt][nt][r] + bv[nt];
                if (relu) val = fmaxf(val, 0.f);
                const size_t idx = m * N + n;
                if (outFz) outFz[idx] = val;
                if (outB) outB[idx] = f2b(val);
            }
        }
    }
}

// ---------------------------------------------------------------------------
// QKV GEMM with fused PoPE/V-transpose epilogue.
// A = xb (4096x1024 bf16), WT = WqkvT (3072x1024), bias = bqkv.
// n<1024: q -> qp (scaled); n<2048: k -> kp; else v -> vt (transposed).
// qp/kp: (B*H, S, 128) bf16;  vt: (B*H, 64, S) bf16.
// ---------------------------------------------------------------------------
__global__ __launch_bounds__(256) void gemm_qkv_pope_kernel(
    const unsigned short* __restrict__ A,
    const unsigned short* __restrict__ WT,
    const float* __restrict__ bias,
    const float* __restrict__ phase_bias, const float* __restrict__ freqs,
    unsigned short* __restrict__ qp, unsigned short* __restrict__ kp,
    unsigned short* __restrict__ vt)
{
    __shared__ unsigned short As[128 * 32];
    __shared__ unsigned short Bs[128 * 32];

    const int tid = threadIdx.x;
    const int w = tid >> 6, lane = tid & 63;
    const int quad = lane >> 4, l16 = lane & 15;
    const size_t m0 = (size_t)blockIdx.y * 128, n0 = (size_t)blockIdx.x * 128;
    const int wm = (w >> 1) * 64, wn = (w & 1) * 64;
    const int K = D_;

    const int srow = w * 32 + (lane >> 2);
    const int schunk = (lane & 3) * 8;
    const unsigned short* ga = A  + (m0 + srow) * K + schunk;
    const unsigned short* gb = WT + (n0 + srow) * K + schunk;
    unsigned short* lA0 = &As[(w * 32) * 32];
    unsigned short* lA1 = &As[(w * 32 + 16) * 32];
    unsigned short* lB0 = &Bs[(w * 32) * 32];
    unsigned short* lB1 = &Bs[(w * 32 + 16) * 32];
    const size_t K16 = (size_t)16 * K;

    f32x4 acc[4][4] = {};

    for (int k0 = 0; k0 < K; k0 += 32) {
        g2l16(ga + k0,       lA0);
        g2l16(ga + K16 + k0, lA1);
        g2l16(gb + k0,       lB0);
        g2l16(gb + K16 + k0, lB1);
        __syncthreads();

        bf16x8 af[4], bfr[4];
        #pragma unroll
        for (int t = 0; t < 4; t++) {
            af[t]  = *(const bf16x8*)&As[(wm + t * 16 + l16) * 32 + quad * 8];
            bfr[t] = *(const bf16x8*)&Bs[(wn + t * 16 + l16) * 32 + quad * 8];
        }
        #pragma unroll
        for (int mt = 0; mt < 4; mt++)
            #pragma unroll
            for (int nt = 0; nt < 4; nt++)
                acc[mt][nt] = MFMA16(af[mt], bfr[nt], acc[mt][nt]);
        __syncthreads();
    }

    float bv[4];
    #pragma unroll
    for (int nt = 0; nt < 4; nt++) bv[nt] = bias[n0 + wn + nt * 16 + l16];

    const int region = (int)(n0 >> 10);   // 0=q, 1=k, 2=v (tile is 128-aligned)

    if (region < 2) {
        unsigned short* dst = (region == 0) ? qp : kp;
        #pragma unroll
        for (int mt = 0; mt < 4; mt++) {
            #pragma unroll
            for (int nt = 0; nt < 4; nt++) {
                const int n = (int)n0 + wn + nt * 16 + l16;
                const int d = n & 63, hh = (n >> 6) & 15;
                const float fr = freqs[d];
                const float pb = phase_bias[hh * 64 + d];
                #pragma unroll
                for (int r = 0; r < 4; r++) {
                    const int m = (int)m0 + wm + mt * 16 + quad * 4 + r;
                    const int s = m & (S_ - 1), bb = m >> 11;
                    float mu = softplus_f(acc[mt][nt][r] + bv[nt]);
                    if (region == 0) mu *= SCALE_;
                    float sn, cs;
                    sincosf((float)s * fr + pb, &sn, &cs);
                    const size_t o = ((size_t)(bb * H_ + hh) * S_ + s) * 128 + d;
                    dst[o]      = f2b(mu * cs);
                    dst[o + 64] = f2b(mu * sn);
                }
            }
        }
    } else {
        #pragma unroll
        for (int mt = 0; mt < 4; mt++) {
            #pragma unroll
            for (int nt = 0; nt < 4; nt++) {
                const int n = (int)n0 + wn + nt * 16 + l16;
                const int d = n & 63, hh = (n - 2048) >> 6;
                ushort4 pk;
                unsigned short* pkp = (unsigned short*)&pk;
                #pragma unroll
                for (int r = 0; r < 4; r++)
                    pkp[r] = f2b(acc[mt][nt][r] + bv[nt]);
                const int mb = (int)m0 + wm + mt * 16 + quad * 4;
                const int s = mb & (S_ - 1), bb = mb >> 11;
                *(ushort4*)&vt[((size_t)(bb * H_ + hh) * 64 + d) * S_ + s] = pk;
            }
        }
    }
}

// ---------------------------------------------------------------------------
// MFMA flash attention, softmax1, LAZY normalization:
// out = (sum_k e^s v) / (e^m + sum_k e^s)  -- all reductions deferred to the
// end (per-lane max/sum accumulators; one shuffle tree per row at the end).
// Causal pairing: block x does q-tiles x and 31-x (uniform 33 k-tiles).
// ---------------------------------------------------------------------------
__global__ __launch_bounds__(256) void attn_mfma_kernel(
    const unsigned short* __restrict__ qp,
    const unsigned short* __restrict__ kp,
    const unsigned short* __restrict__ vt,
    unsigned short* __restrict__ ao)
{
    __shared__ unsigned short kt_lds[64][128];  // [key][k], chunks swizzled by key&15
    __shared__ unsigned short vt_lds[64][64];   // [d][key], chunks swizzled by d&7
    __shared__ unsigned short p_lds[4][16][72]; // per-wave P roundtrip

    const int tid = threadIdx.x;
    const int w = tid >> 6, lane = tid & 63;
    const int quad = lane >> 4, l16 = lane & 15;
    const int bh = blockIdx.y, b = bh >> 4, h = bh & 15;

    const int krow = lane >> 4, kslot = lane & 15;
    const int vrow = lane >> 3, vslot = lane & 7;

    #pragma unroll 1
    for (int part = 0; part < 2; part++) {
        const int a = part == 0 ? (int)blockIdx.x : 31 - (int)blockIdx.x;
        const int q0b = a * 64;
        const int q0 = q0b + w * 16;

        const unsigned short* qbase = qp + ((size_t)bh * S_ + q0 + l16) * 128 + quad * 8;
        bf16x8 qa[4];
        #pragma unroll
        for (int kc = 0; kc < 4; kc++) qa[kc] = *(const bf16x8*)(qbase + kc * 32);

        f32x4 o[4] = {};
        float m_l[4] = {-1e30f, -1e30f, -1e30f, -1e30f};
        float l_l[4] = {0.f, 0.f, 0.f, 0.f};

        for (int t0 = 0; t0 <= q0b; t0 += 64) {
            // stage K (64x128)
            #pragma unroll
            for (int j = 0; j < 4; j++) {
                int r = w * 16 + j * 4 + krow;
                int c = kslot ^ (r & 15);
                g2l16(kp + ((size_t)bh * S_ + t0 + r) * 128 + c * 8, &kt_lds[w * 16 + j * 4][0]);
            }
            // stage Vt (64x64)
            #pragma unroll
            for (int j = 0; j < 2; j++) {
                int d = w * 16 + j * 8 + vrow;
                int c = vslot ^ (d & 7);
                g2l16(vt + ((size_t)bh * 64 + d) * S_ + t0 + c * 8, &vt_lds[w * 16 + j * 8][0]);
            }
            __syncthreads();

            // QK^T
            f32x4 sf[4];
            #pragma unroll
            for (int kg = 0; kg < 4; kg++) {
                f32x4 s = {0, 0, 0, 0};
                const int row = kg * 16 + l16;
                #pragma unroll
                for (int kc = 0; kc < 4; kc++) {
                    const int slot = (kc * 4 + quad) ^ l16;
                    s = MFMA16(qa[kc], *(const bf16x8*)&kt_lds[row][slot * 8], s);
                }
                sf[kg] = s;
            }

            // lazy softmax: per-lane accumulate only
            const bool dmask = (t0 + 63 > q0);
            #pragma unroll
            for (int r = 0; r < 4; r++) {
                const int qrow = q0 + quad * 4 + r;
                float v0 = sf[0][r], v1 = sf[1][r], v2 = sf[2][r], v3 = sf[3][r];
                if (dmask) {
                    v0 = (t0 + l16      <= qrow) ? v0 : -1e30f;
                    v1 = (t0 + 16 + l16 <= qrow) ? v1 : -1e30f;
                    v2 = (t0 + 32 + l16 <= qrow) ? v2 : -1e30f;
                    v3 = (t0 + 48 + l16 <= qrow) ? v3 : -1e30f;
                }
                m_l[r] = fmaxf(m_l[r], fmaxf(fmaxf(v0, v1), fmaxf(v2, v3)));
                const float e0 = __expf(v0), e1 = __expf(v1);
                const float e2 = __expf(v2), e3 = __expf(v3);
                l_l[r] += (e0 + e1) + (e2 + e3);
                p_lds[w][quad * 4 + r][l16]      = f2b(e0);
                p_lds[w][quad * 4 + r][l16 + 16] = f2b(e1);
                p_lds[w][quad * 4 + r][l16 + 32] = f2b(e2);
                p_lds[w][quad * 4 + r][l16 + 48] = f2b(e3);
            }
            asm volatile("s_waitcnt lgkmcnt(0)" ::: "memory");
            bf16x8 pa0 = *(const bf16x8*)&p_lds[w][l16][quad * 8];
            bf16x8 pa1 = *(const bf16x8*)&p_lds[w][l16][quad * 8 + 32];

            // PV (no rescale!)
            #pragma unroll
            for (int dg = 0; dg < 4; dg++) {
                const int row = dg * 16 + l16;
                const int s0_ = quad ^ (l16 & 7);
                const int s1_ = (quad + 4) ^ (l16 & 7);
                o[dg] = MFMA16(pa0, *(const bf16x8*)&vt_lds[row][s0_ * 8], o[dg]);
                o[dg] = MFMA16(pa1, *(const bf16x8*)&vt_lds[row][s1_ * 8], o[dg]);
            }
            __syncthreads();
        }

        // final reductions over the 16-lane key groups + store
        #pragma unroll
        for (int r = 0; r < 4; r++) {
            float mv = m_l[r], lv = l_l[r];
            #pragma unroll
            for (int off = 8; off >= 1; off >>= 1) {
                mv = fmaxf(mv, __shfl_xor(mv, off, 64));
                lv += __shfl_xor(lv, off, 64);
            }
            const float inv = 1.f / (__expf(mv) + lv);
            const int row = q0 + quad * 4 + r;
            const size_t base = (size_t)(b * S_ + row) * D_ + h * HD_ + l16;
            ao[base]      = f2b(o[0][r] * inv);
            ao[base + 16] = f2b(o[1][r] * inv);
            ao[base + 32] = f2b(o[2][r] * inv);
            ao[base + 48] = f2b(o[3][r] * inv);
        }
    }
}

// ---------------------------------------------------------------------------
// Residual + LayerNorm over (ya [+ yb] + res); optional bf16 secondary out.
// ---------------------------------------------------------------------------
__global__ __launch_bounds__(256) void ln_kernel(
    const float* __restrict__ ya, const float* __restrict__ yb,
    const float* __restrict__ res,
    const float* __restrict__ g, const float* __restrict__ beta,
    float* __restrict__ out, unsigned short* __restrict__ outB)
{
    const int row = blockIdx.x;
    const int tid = threadIdx.x;
    const float* yr = ya + (size_t)row * D_;
    const float* y2 = yb ? yb + (size_t)row * D_ : nullptr;
    const float* rr = res + (size_t)row * D_;

    float t[4];
    float sum = 0.f, sumsq = 0.f;
    #pragma unroll
    for (int i = 0; i < 4; i++) {
        int c = tid + 256 * i;
        t[i] = yr[c] + rr[c] + (y2 ? y2[c] : 0.f);
        sum += t[i]; sumsq += t[i] * t[i];
    }
    #pragma unroll
    for (int off = 32; off >= 1; off >>= 1) {
        sum   += __shfl_xor(sum,   off, 64);
        sumsq += __shfl_xor(sumsq, off, 64);
    }
    __shared__ float rs_[4], rq_[4];
    int w = tid >> 6, lane = tid & 63;
    if (lane == 0) { rs_[w] = sum; rq_[w] = sumsq; }
    __syncthreads();
    float tot  = rs_[0] + rs_[1] + rs_[2] + rs_[3];
    float totq = rq_[0] + rq_[1] + rq_[2] + rq_[3];
    float mu   = tot  * (1.f / D_);
    float var  = totq * (1.f / D_) - mu * mu;
    float rstd = rsqrtf(var + 1e-5f);

    float* orow = out + (size_t)row * D_;
    #pragma unroll
    for (int i = 0; i < 4; i++) {
        int c = tid + 256 * i;
        float val = (t[i] - mu) * rstd * g[c] + beta[c];
        orow[c] = val;
        if (outB) outB[(size_t)row * D_ + c] = f2b(val);
    }
}

// ---------------------------------------------------------------------------
extern "C" void kernel_launch(void* const* d_in, const int* in_sizes, int n_in,
                              void* d_out, int out_size, void* d_ws, size_t ws_size,
                              hipStream_t stream)
{
    const float* x   = (const float*)d_in[0];
    const float* Wq  = (const float*)d_in[2];
    const float* bq  = (const float*)d_in[3];
    const float* Wk  = (const float*)d_in[4];
    const float* bk  = (const float*)d_in[5];
    const float* Wv  = (const float*)d_in[6];
    const float* bv  = (const float*)d_in[7];
    const float* Wo  = (const float*)d_in[8];
    const float* bo  = (const float*)d_in[9];
    const float* phase_bias = (const float*)d_in[10];
    const float* freqs = (const float*)d_in[11];
    const float* W1  = (const float*)d_in[12];
    const float* b1  = (const float*)d_in[13];
    const float* W2  = (const float*)d_in[14];
    const float* b2  = (const float*)d_in[15];
    const float* g1  = (const float*)d_in[16];
    const float* be1 = (const float*)d_in[17];
    const float* g2  = (const float*)d_in[18];
    const float* be2 = (const float*)d_in[19];
    float* out = (float*)d_out;

    char* base = (char*)d_ws;
    const size_t MiB = 1024 * 1024;
    unsigned short* WqkvT = (unsigned short*)(base);             // [0,6)
    unsigned short* WoT   = (unsigned short*)(base + 6  * MiB);  // [6,8)
    unsigned short* W1T   = (unsigned short*)(base + 8  * MiB);  // [8,16)
    unsigned short* W2T   = (unsigned short*)(base + 16 * MiB);  // [16,24)
    float*          bqkv  = (float*)(base + 24 * MiB);           // [24,25)
    unsigned short* xb    = (unsigned short*)(base + 25 * MiB);  // [25,33) -> aob
    unsigned short* qpb   = (unsigned short*)(base + 33 * MiB);  // [33,49) -> hb
    unsigned short* kpb   = (unsigned short*)(base + 49 * MiB);  // [49,65) -> hb
    unsigned short* vtb   = (unsigned short*)(base + 65 * MiB);  // [65,73) -> po
    float*          po    = (float*)(base + 65 * MiB);           // [65,97) 2 slices
    float*          x1    = (float*)(base + 97 * MiB);           // [97,113)
    unsigned short* x1b   = (unsigned short*)(base + 113 * MiB); // [113,121)
    unsigned short* aob   = xb;
    unsigned short* hb    = qpb;   // 32 MiB spans qpb+kpb
    float*          fo    = po;    // FFN2 slices reuse po

    dim3 blk(256);

    // prep
    conv_bf16_kernel<<<dim3(M_ * D_ / 256), blk, 0, stream>>>(x, xb);
    wtrans_kernel<<<dim3(32, 32), blk, 0, stream>>>(Wq, WqkvT, D_, D_);
    wtrans_kernel<<<dim3(32, 32), blk, 0, stream>>>(Wk, WqkvT + (size_t)1024 * 1024, D_, D_);
    wtrans_kernel<<<dim3(32, 32), blk, 0, stream>>>(Wv, WqkvT + (size_t)2048 * 1024, D_, D_);
    wtrans_kernel<<<dim3(32, 32), blk, 0, stream>>>(Wo, WoT, D_, D_);
    wtrans_kernel<<<dim3(DFF_ / 32, D_ / 32), blk, 0, stream>>>(W1, W1T, D_, DFF_);
    wtrans_kernel<<<dim3(D_ / 32, DFF_ / 32), blk, 0, stream>>>(W2, W2T, DFF_, D_);
    bcat_kernel<<<dim3(12), blk, 0, stream>>>(bq, bk, bv, bqkv);

    // fused QKV projection + PoPE + V-transpose
    gemm_qkv_pope_kernel<<<dim3(3072 / 128, M_ / 128), blk, 0, stream>>>(
        xb, WqkvT, bqkv, phase_bias, freqs, qpb, kpb, vtb);

    // Flash attention (causal-paired blocks)
    attn_mfma_kernel<<<dim3(16, B_ * H_), blk, 0, stream>>>(qpb, kpb, vtb, aob);

    // Output projection (split-K=2) + LN1
    gemm_bf16_kernel<<<dim3(D_ / 128, M_ / 128, 2), blk, 0, stream>>>(
        aob, WoT, bo, po, nullptr, M_, D_ / 2, D_, D_, 0);
    ln_kernel<<<dim3(M_), blk, 0, stream>>>(po, po + (size_t)M_ * D_, x, g1, be1, x1, x1b);

    // FFN
    gemm_bf16_kernel<<<dim3(DFF_ / 128, M_ / 128, 1), blk, 0, stream>>>(
        x1b, W1T, b1, nullptr, hb, M_, D_, D_, DFF_, 1);
    gemm_bf16_kernel<<<dim3(D_ / 128, M_ / 128, 2), blk, 0, stream>>>(
        hb, W2T, b2, fo, nullptr, M_, DFF_ / 2, DFF_, D_, 0);
    ln_kernel<<<dim3(M_), blk, 0, stream>>>(fo, fo + (size_t)M_ * D_, x1, g2, be2, out, nullptr);
}

// Round 6
// 461.399 us; speedup vs baseline: 1.8004x; 1.8004x over previous
//
#include <hip/hip_runtime.h>
#include <hip/hip_bf16.h>
#include <math.h>

#define B_   2
#define S_   2048
#define D_   1024
#define H_   16
#define HD_  64
#define DFF_ 4096
#define M_   (B_*S_)   // 4096 rows
#define SCALE_ 0.08838834764831845f  // 1/sqrt(128)

typedef __attribute__((ext_vector_type(8))) short bf16x8;
typedef __attribute__((ext_vector_type(4))) float f32x4;

#define MFMA16(a,b,c) __builtin_amdgcn_mfma_f32_16x16x32_bf16((a),(b),(c),0,0,0)

__device__ __forceinline__ unsigned short f2b(float f) {
    union { float f; unsigned u; } v; v.f = f;
    return (unsigned short)((v.u + 0x7FFFu + ((v.u >> 16) & 1u)) >> 16);
}
__device__ __forceinline__ float b2f(unsigned short s) {
    union { unsigned u; float f; } v; v.u = ((unsigned)s) << 16;
    return v.f;
}
__device__ __forceinline__ float softplus_f(float x) {
    return fmaxf(x, 0.f) + log1pf(__expf(-fabsf(x)));
}
// async global->LDS, 16B per lane. LDS dest = base + lane*16 (wave-uniform base).
__device__ __forceinline__ void g2l16(const void* g, void* l) {
    __builtin_amdgcn_global_load_lds(
        (const __attribute__((address_space(1))) unsigned int*)g,
        (__attribute__((address_space(3))) unsigned int*)l, 16, 0, 0);
}

// ---------------------------------------------------------------------------
__global__ __launch_bounds__(256) void conv_bf16_kernel(
    const float* __restrict__ in, unsigned short* __restrict__ out)
{
    int i = blockIdx.x * 256 + threadIdx.x;
    out[i] = f2b(in[i]);
}

// ---------------------------------------------------------------------------
// Weight transpose + bf16: W[K][N] fp32 -> WT[N][K] bf16
// ---------------------------------------------------------------------------
__global__ __launch_bounds__(256) void wtrans_kernel(
    const float* __restrict__ W, unsigned short* __restrict__ WT, int K, int N)
{
    __shared__ float tile[32][33];
    const int n0 = blockIdx.x * 32, k0 = blockIdx.y * 32;
    const int tx = threadIdx.x & 31, ty = threadIdx.x >> 5;  // ty 0..7
    #pragma unroll
    for (int i = 0; i < 4; i++)
        tile[ty + 8*i][tx] = W[(size_t)(k0 + ty + 8*i) * N + n0 + tx];
    __syncthreads();
    #pragma unroll
    for (int i = 0; i < 4; i++)
        WT[(size_t)(n0 + ty + 8*i) * K + k0 + tx] = f2b(tile[tx][ty + 8*i]);
}

// ---------------------------------------------------------------------------
__global__ __launch_bounds__(256) void bcat_kernel(
    const float* __restrict__ a, const float* __restrict__ b,
    const float* __restrict__ c, float* __restrict__ o)
{
    int i = blockIdx.x * 256 + threadIdx.x;
    o[i] = (i < 1024) ? a[i] : (i < 2048 ? b[i - 1024] : c[i - 2048]);
}

// ---------------------------------------------------------------------------
// m97-style bf16 GEMM with optional split-K (gridDim.z slices).
// C[M,N] = A[M,lda] @ WT[N,lda]^T (+bias on z=0), opt relu.
// 128x128 tile, BK=32, staging via global_load_lds width=16.
// ---------------------------------------------------------------------------
__global__ __launch_bounds__(256) void gemm_bf16_kernel(
    const unsigned short* __restrict__ A,
    const unsigned short* __restrict__ WT,
    const float* __restrict__ bias,
    float* __restrict__ outF, unsigned short* __restrict__ outB,
    int M, int Kslice, int lda, int N, int relu)
{
    __shared__ unsigned short As[128 * 32];
    __shared__ unsigned short Bs[128 * 32];

    const int tid = threadIdx.x;
    const int w = tid >> 6, lane = tid & 63;
    const int quad = lane >> 4, l16 = lane & 15;
    const size_t m0 = (size_t)blockIdx.y * 128, n0 = (size_t)blockIdx.x * 128;
    const int wm = (w >> 1) * 64, wn = (w & 1) * 64;
    const int koff = blockIdx.z * Kslice;

    const int srow = w * 32 + (lane >> 2);
    const int schunk = (lane & 3) * 8;
    const unsigned short* ga = A  + (m0 + srow) * lda + koff + schunk;
    const unsigned short* gb = WT + (n0 + srow) * lda + koff + schunk;
    unsigned short* lA0 = &As[(w * 32) * 32];
    unsigned short* lA1 = &As[(w * 32 + 16) * 32];
    unsigned short* lB0 = &Bs[(w * 32) * 32];
    unsigned short* lB1 = &Bs[(w * 32 + 16) * 32];
    const size_t K16 = (size_t)16 * lda;

    f32x4 acc[4][4] = {};

    for (int k0 = 0; k0 < Kslice; k0 += 32) {
        g2l16(ga + k0,       lA0);
        g2l16(ga + K16 + k0, lA1);
        g2l16(gb + k0,       lB0);
        g2l16(gb + K16 + k0, lB1);
        __syncthreads();

        bf16x8 af[4], bfr[4];
        #pragma unroll
        for (int t = 0; t < 4; t++) {
            af[t]  = *(const bf16x8*)&As[(wm + t * 16 + l16) * 32 + quad * 8];
            bfr[t] = *(const bf16x8*)&Bs[(wn + t * 16 + l16) * 32 + quad * 8];
        }
        #pragma unroll
        for (int mt = 0; mt < 4; mt++)
            #pragma unroll
            for (int nt = 0; nt < 4; nt++)
                acc[mt][nt] = MFMA16(af[mt], bfr[nt], acc[mt][nt]);
        __syncthreads();
    }

    float bv[4];
    #pragma unroll
    for (int nt = 0; nt < 4; nt++)
        bv[nt] = (blockIdx.z == 0) ? bias[n0 + wn + nt * 16 + l16] : 0.f;

    float* outFz = outF ? outF + (size_t)blockIdx.z * M * N : nullptr;

    #pragma unroll
    for (int mt = 0; mt < 4; mt++) {
        #pragma unroll
        for (int nt = 0; nt < 4; nt++) {
            const size_t n = n0 + wn + nt * 16 + l16;
            #pragma unroll
            for (int r = 0; r < 4; r++) {
                const size_t m = m0 + wm + mt * 16 + quad * 4 + r;
                float val = acc[mt][nt][r] + bv[nt];
                if (relu) val = fmaxf(val, 0.f);
                const size_t idx = m * N + n;
                if (outFz) outFz[idx] = val;
                if (outB) outB[idx] = f2b(val);
            }
        }
    }
}

// ---------------------------------------------------------------------------
// PoPE: qkvb bf16 (B,S,3072) -> bf16 qp,kp (B*H, S, 128). Q pre-scaled.
// Wave-contiguous stores (128B per instruction).
// ---------------------------------------------------------------------------
__global__ __launch_bounds__(256) void pope_kernel(
    const unsigned short* __restrict__ qkv,
    const float* __restrict__ phase_bias, const float* __restrict__ freqs,
    unsigned short* __restrict__ qp, unsigned short* __restrict__ kp)
{
    int idx = blockIdx.x * 256 + threadIdx.x;   // over B*H*S*HD = 4M
    int d = idx & 63;
    int s = (idx >> 6) & (S_ - 1);
    int h = (idx >> 17) & (H_ - 1);
    int b = idx >> 21;

    size_t src = (size_t)(b * S_ + s) * 3072 + h * HD_ + d;
    float muq = softplus_f(b2f(qkv[src])) * SCALE_;
    float muk = softplus_f(b2f(qkv[src + 1024]));

    float ph = (float)s * freqs[d] + phase_bias[h * HD_ + d];
    float sn, cs;
    sincosf(ph, &sn, &cs);

    size_t o = ((size_t)(b * H_ + h) * S_ + s) * 128 + d;
    qp[o]      = f2b(muq * cs);
    qp[o + 64] = f2b(muq * sn);
    kp[o]      = f2b(muk * cs);
    kp[o + 64] = f2b(muk * sn);
}

// ---------------------------------------------------------------------------
// V transpose: qkvb bf16 (B,S,3072) col 2048.. -> vt bf16 (B*H, 64, S)
// ---------------------------------------------------------------------------
__global__ __launch_bounds__(256) void vtrans_kernel(
    const unsigned short* __restrict__ qkv, unsigned short* __restrict__ vt)
{
    __shared__ unsigned short tile[64][72];
    const int bh = blockIdx.y, b = bh >> 4, h = bh & 15;
    const int s0 = blockIdx.x * 64;
    const int tid = threadIdx.x;
    #pragma unroll
    for (int i = 0; i < 16; i++) {
        int idx = i * 256 + tid;
        int s = idx >> 6, d = idx & 63;
        tile[s][d] = qkv[(size_t)(b * S_ + s0 + s) * 3072 + 2048 + h * HD_ + d];
    }
    __syncthreads();
    #pragma unroll
    for (int i = 0; i < 16; i++) {
        int idx = i * 256 + tid;
        int d = idx >> 6, s = idx & 63;
        vt[((size_t)bh * 64 + d) * S_ + s0 + s] = tile[s][d];
    }
}

// ---------------------------------------------------------------------------
// MFMA flash attention, softmax1, LAZY normalization:
// out = (sum_k e^s v) / (e^m + sum_k e^s). Per-lane max/sum accumulators;
// one shuffle tree per row at the end. Causal pairing: block x does q-tiles
// x and 31-x (uniform 33 k-tiles per block).
// ---------------------------------------------------------------------------
__global__ __launch_bounds__(256) void attn_mfma_kernel(
    const unsigned short* __restrict__ qp,
    const unsigned short* __restrict__ kp,
    const unsigned short* __restrict__ vt,
    unsigned short* __restrict__ ao)
{
    __shared__ unsigned short kt_lds[64][128];  // [key][k], chunks swizzled by key&15
    __shared__ unsigned short vt_lds[64][64];   // [d][key], chunks swizzled by d&7
    __shared__ unsigned short p_lds[4][16][72]; // per-wave P roundtrip

    const int tid = threadIdx.x;
    const int w = tid >> 6, lane = tid & 63;
    const int quad = lane >> 4, l16 = lane & 15;
    const int bh = blockIdx.y, b = bh >> 4, h = bh & 15;

    const int krow = lane >> 4, kslot = lane & 15;
    const int vrow = lane >> 3, vslot = lane & 7;

    #pragma unroll 1
    for (int part = 0; part < 2; part++) {
        const int a = part == 0 ? (int)blockIdx.x : 31 - (int)blockIdx.x;
        const int q0b = a * 64;
        const int q0 = q0b + w * 16;

        const unsigned short* qbase = qp + ((size_t)bh * S_ + q0 + l16) * 128 + quad * 8;
        bf16x8 qa[4];
        #pragma unroll
        for (int kc = 0; kc < 4; kc++) qa[kc] = *(const bf16x8*)(qbase + kc * 32);

        f32x4 o[4] = {};
        float m_l[4] = {-1e30f, -1e30f, -1e30f, -1e30f};
        float l_l[4] = {0.f, 0.f, 0.f, 0.f};

        for (int t0 = 0; t0 <= q0b; t0 += 64) {
            // stage K (64x128)
            #pragma unroll
            for (int j = 0; j < 4; j++) {
                int r = w * 16 + j * 4 + krow;
                int c = kslot ^ (r & 15);
                g2l16(kp + ((size_t)bh * S_ + t0 + r) * 128 + c * 8, &kt_lds[w * 16 + j * 4][0]);
            }
            // stage Vt (64x64)
            #pragma unroll
            for (int j = 0; j < 2; j++) {
                int d = w * 16 + j * 8 + vrow;
                int c = vslot ^ (d & 7);
                g2l16(vt + ((size_t)bh * 64 + d) * S_ + t0 + c * 8, &vt_lds[w * 16 + j * 8][0]);
            }
            __syncthreads();

            // QK^T
            f32x4 sf[4];
            #pragma unroll
            for (int kg = 0; kg < 4; kg++) {
                f32x4 s = {0, 0, 0, 0};
                const int row = kg * 16 + l16;
                #pragma unroll
                for (int kc = 0; kc < 4; kc++) {
                    const int slot = (kc * 4 + quad) ^ l16;
                    s = MFMA16(qa[kc], *(const bf16x8*)&kt_lds[row][slot * 8], s);
                }
                sf[kg] = s;
            }

            // lazy softmax: per-lane accumulate only
            const bool dmask = (t0 + 63 > q0);
            #pragma unroll
            for (int r = 0; r < 4; r++) {
                const int qrow = q0 + quad * 4 + r;
                float v0 = sf[0][r], v1 = sf[1][r], v2 = sf[2][r], v3 = sf[3][r];
                if (dmask) {
                    v0 = (t0 + l16      <= qrow) ? v0 : -1e30f;
                    v1 = (t0 + 16 + l16 <= qrow) ? v1 : -1e30f;
                    v2 = (t0 + 32 + l16 <= qrow) ? v2 : -1e30f;
                    v3 = (t0 + 48 + l16 <= qrow) ? v3 : -1e30f;
                }
                m_l[r] = fmaxf(m_l[r], fmaxf(fmaxf(v0, v1), fmaxf(v2, v3)));
                const float e0 = __expf(v0), e1 = __expf(v1);
                const float e2 = __expf(v2), e3 = __expf(v3);
                l_l[r] += (e0 + e1) + (e2 + e3);
                p_lds[w][quad * 4 + r][l16]      = f2b(e0);
                p_lds[w][quad * 4 + r][l16 + 16] = f2b(e1);
                p_lds[w][quad * 4 + r][l16 + 32] = f2b(e2);
                p_lds[w][quad * 4 + r][l16 + 48] = f2b(e3);
            }
            asm volatile("s_waitcnt lgkmcnt(0)" ::: "memory");
            bf16x8 pa0 = *(const bf16x8*)&p_lds[w][l16][quad * 8];
            bf16x8 pa1 = *(const bf16x8*)&p_lds[w][l16][quad * 8 + 32];

            // PV (no rescale)
            #pragma unroll
            for (int dg = 0; dg < 4; dg++) {
                const int row = dg * 16 + l16;
                const int s0_ = quad ^ (l16 & 7);
                const int s1_ = (quad + 4) ^ (l16 & 7);
                o[dg] = MFMA16(pa0, *(const bf16x8*)&vt_lds[row][s0_ * 8], o[dg]);
                o[dg] = MFMA16(pa1, *(const bf16x8*)&vt_lds[row][s1_ * 8], o[dg]);
            }
            __syncthreads();
        }

        // final reductions + store
        #pragma unroll
        for (int r = 0; r < 4; r++) {
            float mv = m_l[r], lv = l_l[r];
            #pragma unroll
            for (int off = 8; off >= 1; off >>= 1) {
                mv = fmaxf(mv, __shfl_xor(mv, off, 64));
                lv += __shfl_xor(lv, off, 64);
            }
            const float inv = 1.f / (__expf(mv) + lv);
            const int row = q0 + quad * 4 + r;
            const size_t base = (size_t)(b * S_ + row) * D_ + h * HD_ + l16;
            ao[base]      = f2b(o[0][r] * inv);
            ao[base + 16] = f2b(o[1][r] * inv);
            ao[base + 32] = f2b(o[2][r] * inv);
            ao[base + 48] = f2b(o[3][r] * inv);
        }
    }
}

// ---------------------------------------------------------------------------
// Residual + LayerNorm over (ya [+ yb] + res); optional bf16 secondary out.
// ---------------------------------------------------------------------------
__global__ __launch_bounds__(256) void ln_kernel(
    const float* __restrict__ ya, const float* __restrict__ yb,
    const float* __restrict__ res,
    const float* __restrict__ g, const float* __restrict__ beta,
    float* __restrict__ out, unsigned short* __restrict__ outB)
{
    const int row = blockIdx.x;
    const int tid = threadIdx.x;
    const float* yr = ya + (size_t)row * D_;
    const float* y2 = yb ? yb + (size_t)row * D_ : nullptr;
    const float* rr = res + (size_t)row * D_;

    float t[4];
    float sum = 0.f, sumsq = 0.f;
    #pragma unroll
    for (int i = 0; i < 4; i++) {
        int c = tid + 256 * i;
        t[i] = yr[c] + rr[c] + (y2 ? y2[c] : 0.f);
        sum += t[i]; sumsq += t[i] * t[i];
    }
    #pragma unroll
    for (int off = 32; off >= 1; off >>= 1) {
        sum   += __shfl_xor(sum,   off, 64);
        sumsq += __shfl_xor(sumsq, off, 64);
    }
    __shared__ float rs_[4], rq_[4];
    int w = tid >> 6, lane = tid & 63;
    if (lane == 0) { rs_[w] = sum; rq_[w] = sumsq; }
    __syncthreads();
    float tot  = rs_[0] + rs_[1] + rs_[2] + rs_[3];
    float totq = rq_[0] + rq_[1] + rq_[2] + rq_[3];
    float mu   = tot  * (1.f / D_);
    float var  = totq * (1.f / D_) - mu * mu;
    float rstd = rsqrtf(var + 1e-5f);

    float* orow = out + (size_t)row * D_;
    #pragma unroll
    for (int i = 0; i < 4; i++) {
        int c = tid + 256 * i;
        float val = (t[i] - mu) * rstd * g[c] + beta[c];
        orow[c] = val;
        if (outB) outB[(size_t)row * D_ + c] = f2b(val);
    }
}

// ---------------------------------------------------------------------------
extern "C" void kernel_launch(void* const* d_in, const int* in_sizes, int n_in,
                              void* d_out, int out_size, void* d_ws, size_t ws_size,
                              hipStream_t stream)
{
    const float* x   = (const float*)d_in[0];
    const float* Wq  = (const float*)d_in[2];
    const float* bq  = (const float*)d_in[3];
    const float* Wk  = (const float*)d_in[4];
    const float* bk  = (const float*)d_in[5];
    const float* Wv  = (const float*)d_in[6];
    const float* bv  = (const float*)d_in[7];
    const float* Wo  = (const float*)d_in[8];
    const float* bo  = (const float*)d_in[9];
    const float* phase_bias = (const float*)d_in[10];
    const float* freqs = (const float*)d_in[11];
    const float* W1  = (const float*)d_in[12];
    const float* b1  = (const float*)d_in[13];
    const float* W2  = (const float*)d_in[14];
    const float* b2  = (const float*)d_in[15];
    const float* g1  = (const float*)d_in[16];
    const float* be1 = (const float*)d_in[17];
    const float* g2  = (const float*)d_in[18];
    const float* be2 = (const float*)d_in[19];
    float* out = (float*)d_out;

    char* base = (char*)d_ws;
    const size_t MiB = 1024 * 1024;
    unsigned short* WqkvT = (unsigned short*)(base);             // [0,6)
    unsigned short* WoT   = (unsigned short*)(base + 6  * MiB);  // [6,8)
    unsigned short* W1T   = (unsigned short*)(base + 8  * MiB);  // [8,16)
    unsigned short* W2T   = (unsigned short*)(base + 16 * MiB);  // [16,24)
    float*          bqkv  = (float*)(base + 24 * MiB);           // [24,25)
    unsigned short* xb    = (unsigned short*)(base + 25 * MiB);  // [25,33)
    unsigned short* qkvb  = (unsigned short*)(base + 33 * MiB);  // [33,57)
    unsigned short* qpb   = (unsigned short*)(base + 57 * MiB);  // [57,73)
    unsigned short* kpb   = (unsigned short*)(base + 73 * MiB);  // [73,89)
    unsigned short* vtb   = (unsigned short*)(base + 89 * MiB);  // [89,97)
    float*          po    = (float*)(base + 89 * MiB);           // [89,121) 2 slices (vtb dead)
    float*          x1    = (float*)(base + 121 * MiB);          // [121,137)
    unsigned short* aob   = xb;                                  // xb dead after QKV gemm
    unsigned short* x1b   = xb;                                  // aob dead after Wo gemm
    unsigned short* hb    = qkvb;                                // [33,65): qkvb+qpb dead
    float*          fo    = po;                                  // po dead after LN1

    dim3 blk(256);

    // prep
    conv_bf16_kernel<<<dim3(M_ * D_ / 256), blk, 0, stream>>>(x, xb);
    wtrans_kernel<<<dim3(32, 32), blk, 0, stream>>>(Wq, WqkvT, D_, D_);
    wtrans_kernel<<<dim3(32, 32), blk, 0, stream>>>(Wk, WqkvT + (size_t)1024 * 1024, D_, D_);
    wtrans_kernel<<<dim3(32, 32), blk, 0, stream>>>(Wv, WqkvT + (size_t)2048 * 1024, D_, D_);
    wtrans_kernel<<<dim3(32, 32), blk, 0, stream>>>(Wo, WoT, D_, D_);
    wtrans_kernel<<<dim3(DFF_ / 32, D_ / 32), blk, 0, stream>>>(W1, W1T, D_, DFF_);
    wtrans_kernel<<<dim3(D_ / 32, DFF_ / 32), blk, 0, stream>>>(W2, W2T, DFF_, D_);
    bcat_kernel<<<dim3(12), blk, 0, stream>>>(bq, bk, bv, bqkv);

    // fused QKV projection -> bf16 qkvb (linear epilogue)
    gemm_bf16_kernel<<<dim3(3072 / 128, M_ / 128, 1), blk, 0, stream>>>(
        xb, WqkvT, bqkv, nullptr, qkvb, M_, D_, D_, 3072, 0);

    // PoPE + V transpose (wave-contiguous stores)
    pope_kernel<<<dim3(B_ * H_ * S_ * HD_ / 256), blk, 0, stream>>>(
        qkvb, phase_bias, freqs, qpb, kpb);
    vtrans_kernel<<<dim3(S_ / 64, B_ * H_), blk, 0, stream>>>(qkvb, vtb);

    // Flash attention (lazy softmax1, causal-paired blocks)
    attn_mfma_kernel<<<dim3(16, B_ * H_), blk, 0, stream>>>(qpb, kpb, vtb, aob);

    // Output projection (split-K=2) + LN1
    gemm_bf16_kernel<<<dim3(D_ / 128, M_ / 128, 2), blk, 0, stream>>>(
        aob, WoT, bo, po, nullptr, M_, D_ / 2, D_, D_, 0);
    ln_kernel<<<dim3(M_), blk, 0, stream>>>(po, po + (size_t)M_ * D_, x, g1, be1, x1, x1b);

    // FFN
    gemm_bf16_kernel<<<dim3(DFF_ / 128, M_ / 128, 1), blk, 0, stream>>>(
        x1b, W1T, b1, nullptr, hb, M_, D_, D_, DFF_, 1);
    gemm_bf16_kernel<<<dim3(D_ / 128, M_ / 128, 2), blk, 0, stream>>>(
        hb, W2T, b2, fo, nullptr, M_, DFF_ / 2, DFF_, D_, 0);
    ln_kernel<<<dim3(M_), blk, 0, stream>>>(fo, fo + (size_t)M_ * D_, x1, g2, be2, out, nullptr);
}

// Round 7
// 426.865 us; speedup vs baseline: 1.9461x; 1.0809x over previous
//
#include <hip/hip_runtime.h>
#include <hip/hip_bf16.h>
#include <math.h>

#define B_   2
#define S_   2048
#define D_   1024
#define H_   16
#define HD_  64
#define DFF_ 4096
#define M_   (B_*S_)   // 4096 rows
#define SCALE_ 0.08838834764831845f  // 1/sqrt(128)

typedef __attribute__((ext_vector_type(8))) short bf16x8;
typedef __attribute__((ext_vector_type(4))) float f32x4;

#define MFMA16(a,b,c) __builtin_amdgcn_mfma_f32_16x16x32_bf16((a),(b),(c),0,0,0)

__device__ __forceinline__ unsigned short f2b(float f) {
    union { float f; unsigned u; } v; v.f = f;
    return (unsigned short)((v.u + 0x7FFFu + ((v.u >> 16) & 1u)) >> 16);
}
__device__ __forceinline__ float b2f(unsigned short s) {
    union { unsigned u; float f; } v; v.u = ((unsigned)s) << 16;
    return v.f;
}
__device__ __forceinline__ float softplus_f(float x) {
    return fmaxf(x, 0.f) + log1pf(__expf(-fabsf(x)));
}
// async global->LDS, 16B per lane. LDS dest = base + lane*16 (wave-uniform base).
__device__ __forceinline__ void g2l16(const void* g, void* l) {
    __builtin_amdgcn_global_load_lds(
        (const __attribute__((address_space(1))) unsigned int*)g,
        (__attribute__((address_space(3))) unsigned int*)l, 16, 0, 0);
}

// ---------------------------------------------------------------------------
__global__ __launch_bounds__(256) void conv_bf16_kernel(
    const float* __restrict__ in, unsigned short* __restrict__ out)
{
    int i = blockIdx.x * 256 + threadIdx.x;
    out[i] = f2b(in[i]);
}

// ---------------------------------------------------------------------------
// Weight transpose + bf16: W[K][N] fp32 -> WT[N][K] bf16
// ---------------------------------------------------------------------------
__global__ __launch_bounds__(256) void wtrans_kernel(
    const float* __restrict__ W, unsigned short* __restrict__ WT, int K, int N)
{
    __shared__ float tile[32][33];
    const int n0 = blockIdx.x * 32, k0 = blockIdx.y * 32;
    const int tx = threadIdx.x & 31, ty = threadIdx.x >> 5;  // ty 0..7
    #pragma unroll
    for (int i = 0; i < 4; i++)
        tile[ty + 8*i][tx] = W[(size_t)(k0 + ty + 8*i) * N + n0 + tx];
    __syncthreads();
    #pragma unroll
    for (int i = 0; i < 4; i++)
        WT[(size_t)(n0 + ty + 8*i) * K + k0 + tx] = f2b(tile[tx][ty + 8*i]);
}

// ---------------------------------------------------------------------------
__global__ __launch_bounds__(256) void bcat_kernel(
    const float* __restrict__ a, const float* __restrict__ b,
    const float* __restrict__ c, float* __restrict__ o)
{
    int i = blockIdx.x * 256 + threadIdx.x;
    o[i] = (i < 1024) ? a[i] : (i < 2048 ? b[i - 1024] : c[i - 2048]);
}

// ---------------------------------------------------------------------------
// bf16 GEMM, BK=64, XOR-swizzled LDS (conflict-free ds_read_b128), optional
// split-K (gridDim.z). C[M,N] = A[M,lda] @ WT[N,lda]^T (+bias on z=0), relu.
// 128x128 tile, 4 waves (2x2) each 64x64.
// LDS layout: [row][64] shorts; chunk c holds global chunk c ^ (row&7).
// ---------------------------------------------------------------------------
__global__ __launch_bounds__(256) void gemm_bf16_kernel(
    const unsigned short* __restrict__ A,
    const unsigned short* __restrict__ WT,
    const float* __restrict__ bias,
    float* __restrict__ outF, unsigned short* __restrict__ outB,
    int M, int Kslice, int lda, int N, int relu)
{
    __shared__ unsigned short As[128 * 64];
    __shared__ unsigned short Bs[128 * 64];

    const int tid = threadIdx.x;
    const int w = tid >> 6, lane = tid & 63;
    const int quad = lane >> 4, l16 = lane & 15;
    const size_t m0 = (size_t)blockIdx.y * 128, n0 = (size_t)blockIdx.x * 128;
    const int wm = (w >> 1) * 64, wn = (w & 1) * 64;
    const int koff = blockIdx.z * Kslice;

    // staging: per wave 4 instrs each for A and B; instr j covers 8 rows.
    const int srow = lane >> 3;                       // 0..7 row within group
    const int sc   = ((lane & 7) ^ srow) * 8;         // swizzled global chunk
    const unsigned short* ga = A  + (m0 + w * 32 + srow) * (size_t)lda + koff + sc;
    const unsigned short* gb = WT + (n0 + w * 32 + srow) * (size_t)lda + koff + sc;
    const size_t rows8 = (size_t)8 * lda;

    f32x4 acc[4][4] = {};

    for (int k0 = 0; k0 < Kslice; k0 += 64) {
        #pragma unroll
        for (int j = 0; j < 4; j++)
            g2l16(ga + j * rows8 + k0, &As[(w * 32 + j * 8) * 64]);
        #pragma unroll
        for (int j = 0; j < 4; j++)
            g2l16(gb + j * rows8 + k0, &Bs[(w * 32 + j * 8) * 64]);
        __syncthreads();

        #pragma unroll
        for (int kk = 0; kk < 2; kk++) {
            bf16x8 af[4], bfr[4];
            #pragma unroll
            for (int t = 0; t < 4; t++) {
                const int slot = ((kk * 4 + quad) ^ (l16 & 7)) * 8;
                af[t]  = *(const bf16x8*)&As[(wm + t * 16 + l16) * 64 + slot];
                bfr[t] = *(const bf16x8*)&Bs[(wn + t * 16 + l16) * 64 + slot];
            }
            #pragma unroll
            for (int mt = 0; mt < 4; mt++)
                #pragma unroll
                for (int nt = 0; nt < 4; nt++)
                    acc[mt][nt] = MFMA16(af[mt], bfr[nt], acc[mt][nt]);
        }
        __syncthreads();
    }

    float bv[4];
    #pragma unroll
    for (int nt = 0; nt < 4; nt++)
        bv[nt] = (blockIdx.z == 0) ? bias[n0 + wn + nt * 16 + l16] : 0.f;

    float* outFz = outF ? outF + (size_t)blockIdx.z * M * N : nullptr;

    #pragma unroll
    for (int mt = 0; mt < 4; mt++) {
        #pragma unroll
        for (int nt = 0; nt < 4; nt++) {
            const size_t n = n0 + wn + nt * 16 + l16;
            #pragma unroll
            for (int r = 0; r < 4; r++) {
                const size_t m = m0 + wm + mt * 16 + quad * 4 + r;
                float val = acc[mt][nt][r] + bv[nt];
                if (relu) val = fmaxf(val, 0.f);
                const size_t idx = m * N + n;
                if (outFz) outFz[idx] = val;
                if (outB) outB[idx] = f2b(val);
            }
        }
    }
}

// ---------------------------------------------------------------------------
// PoPE: qkvb bf16 (B,S,3072) -> bf16 qp,kp (B*H, S, 128). Q pre-scaled.
// ---------------------------------------------------------------------------
__global__ __launch_bounds__(256) void pope_kernel(
    const unsigned short* __restrict__ qkv,
    const float* __restrict__ phase_bias, const float* __restrict__ freqs,
    unsigned short* __restrict__ qp, unsigned short* __restrict__ kp)
{
    int idx = blockIdx.x * 256 + threadIdx.x;   // over B*H*S*HD = 4M
    int d = idx & 63;
    int s = (idx >> 6) & (S_ - 1);
    int h = (idx >> 17) & (H_ - 1);
    int b = idx >> 21;

    size_t src = (size_t)(b * S_ + s) * 3072 + h * HD_ + d;
    float muq = softplus_f(b2f(qkv[src])) * SCALE_;
    float muk = softplus_f(b2f(qkv[src + 1024]));

    float ph = (float)s * freqs[d] + phase_bias[h * HD_ + d];
    float sn, cs;
    sincosf(ph, &sn, &cs);

    size_t o = ((size_t)(b * H_ + h) * S_ + s) * 128 + d;
    qp[o]      = f2b(muq * cs);
    qp[o + 64] = f2b(muq * sn);
    kp[o]      = f2b(muk * cs);
    kp[o + 64] = f2b(muk * sn);
}

// ---------------------------------------------------------------------------
// V transpose: qkvb bf16 (B,S,3072) col 2048.. -> vt bf16 (B*H, 64, S)
// ---------------------------------------------------------------------------
__global__ __launch_bounds__(256) void vtrans_kernel(
    const unsigned short* __restrict__ qkv, unsigned short* __restrict__ vt)
{
    __shared__ unsigned short tile[64][72];
    const int bh = blockIdx.y, b = bh >> 4, h = bh & 15;
    const int s0 = blockIdx.x * 64;
    const int tid = threadIdx.x;
    #pragma unroll
    for (int i = 0; i < 16; i++) {
        int idx = i * 256 + tid;
        int s = idx >> 6, d = idx & 63;
        tile[s][d] = qkv[(size_t)(b * S_ + s0 + s) * 3072 + 2048 + h * HD_ + d];
    }
    __syncthreads();
    #pragma unroll
    for (int i = 0; i < 16; i++) {
        int idx = i * 256 + tid;
        int d = idx >> 6, s = idx & 63;
        vt[((size_t)bh * 64 + d) * S_ + s0 + s] = tile[s][d];
    }
}

// ---------------------------------------------------------------------------
// MFMA flash attention, softmax1, lazy normalization, S^T trick:
// QK^T computed transposed (A=K, B=Q) so each lane's 4 scores are
// key-adjacent -> one ushort4 P-store per kg and per-lane scalar m/l.
// Block = 128 q rows (8 waves x 16). K/V staged double-buffered (one
// barrier per tile; prefetch overlaps compute). Causal pairing over 16
// q-tiles: block x does tiles x and 15-x (uniform 34 k-tiles).
// ---------------------------------------------------------------------------
__global__ __launch_bounds__(512) void attn_mfma_kernel(
    const unsigned short* __restrict__ qp,
    const unsigned short* __restrict__ kp,
    const unsigned short* __restrict__ vt,
    unsigned short* __restrict__ ao)
{
    __shared__ unsigned short kt_lds[2][64][128];  // [buf][key][k], chunk^=(key&15)
    __shared__ unsigned short vt_lds[2][64][64];   // [buf][d][key], chunk^=(d&7)
    __shared__ unsigned short p_lds[8][16][72];    // per-wave P: [q][key]

    const int tid = threadIdx.x;
    const int w = tid >> 6, lane = tid & 63;
    const int quad = lane >> 4, l16 = lane & 15;
    const int bh = blockIdx.y, b = bh >> 4, h = bh & 15;

    const int krow = lane >> 4, kslot = lane & 15;   // K staging: 4 rows/instr
    const int vrow = lane >> 3, vslot = lane & 7;    // V staging: 8 rows/instr

    #pragma unroll 1
    for (int part = 0; part < 2; part++) {
        const int a = part == 0 ? (int)blockIdx.x : 15 - (int)blockIdx.x;
        const int q0b = a * 128;
        const int q0 = q0b + w * 16;

        const unsigned short* qbase = qp + ((size_t)bh * S_ + q0 + l16) * 128 + quad * 8;
        bf16x8 qa[4];
        #pragma unroll
        for (int kc = 0; kc < 4; kc++) qa[kc] = *(const bf16x8*)(qbase + kc * 32);

        f32x4 o[4] = {};
        float ms = -1e30f, ls = 0.f;

        const int ntiles = (q0b >> 6) + 2;

        __syncthreads();   // protect LDS from previous part's reads
        // stage tile 0 -> buf 0
        #pragma unroll
        for (int j = 0; j < 2; j++) {
            const int r = w * 8 + j * 4 + krow;
            const int c = kslot ^ (r & 15);
            g2l16(kp + ((size_t)bh * S_ + r) * 128 + c * 8, &kt_lds[0][w * 8 + j * 4][0]);
        }
        {
            const int d = w * 8 + vrow;
            const int c = vslot ^ (d & 7);
            g2l16(vt + ((size_t)bh * 64 + d) * S_ + c * 8, &vt_lds[0][w * 8][0]);
        }

        for (int ti = 0; ti < ntiles; ti++) {
            const int t0 = ti * 64;
            __syncthreads();   // drains this tile's staging; frees other buf
            if (ti + 1 < ntiles) {
                const int nb = (ti + 1) & 1, nt0 = t0 + 64;
                #pragma unroll
                for (int j = 0; j < 2; j++) {
                    const int r = w * 8 + j * 4 + krow;
                    const int c = kslot ^ (r & 15);
                    g2l16(kp + ((size_t)bh * S_ + nt0 + r) * 128 + c * 8,
                          &kt_lds[nb][w * 8 + j * 4][0]);
                }
                {
                    const int d = w * 8 + vrow;
                    const int c = vslot ^ (d & 7);
                    g2l16(vt + ((size_t)bh * 64 + d) * S_ + nt0 + c * 8,
                          &vt_lds[nb][w * 8][0]);
                }
            }
            const int buf = ti & 1;

            if (t0 <= q0 + 15) {   // wave-uniform causal skip
                // QK^T transposed: A = K-frag (rows=keys), B = Q-frag
                f32x4 sf[4];
                #pragma unroll
                for (int kg = 0; kg < 4; kg++) {
                    f32x4 s = {0, 0, 0, 0};
                    const int row = kg * 16 + l16;
                    #pragma unroll
                    for (int kc = 0; kc < 4; kc++) {
                        const int slot = (kc * 4 + quad) ^ l16;
                        s = MFMA16(*(const bf16x8*)&kt_lds[buf][row][slot * 8], qa[kc], s);
                    }
                    sf[kg] = s;   // sf[kg][r] = score(key=t0+kg*16+quad*4+r, q=q0+l16)
                }

                // mask + exp, packed P store (4 adjacent keys per lane)
                const int qrow = q0 + l16;
                #pragma unroll
                for (int kg = 0; kg < 4; kg++) {
                    const int kbase = t0 + kg * 16 + quad * 4;
                    ushort4 pk;
                    unsigned short* pkp = (unsigned short*)&pk;
                    float esum = 0.f;
                    #pragma unroll
                    for (int r = 0; r < 4; r++) {
                        const float v = (kbase + r <= qrow) ? sf[kg][r] : -1e30f;
                        ms = fmaxf(ms, v);
                        const float e = __expf(v);
                        esum += e;
                        pkp[r] = f2b(e);
                    }
                    ls += esum;
                    *(ushort4*)&p_lds[w][l16][kg * 16 + quad * 4] = pk;
                }
                asm volatile("s_waitcnt lgkmcnt(0)" ::: "memory");
                bf16x8 pa0 = *(const bf16x8*)&p_lds[w][l16][quad * 8];
                bf16x8 pa1 = *(const bf16x8*)&p_lds[w][l16][quad * 8 + 32];

                // PV
                #pragma unroll
                for (int dg = 0; dg < 4; dg++) {
                    const int row = dg * 16 + l16;
                    const int s0_ = quad ^ (l16 & 7);
                    const int s1_ = (quad + 4) ^ (l16 & 7);
                    o[dg] = MFMA16(pa0, *(const bf16x8*)&vt_lds[buf][row][s0_ * 8], o[dg]);
                    o[dg] = MFMA16(pa1, *(const bf16x8*)&vt_lds[buf][row][s1_ * 8], o[dg]);
                }
            }
        }

        // cross-quad reduction (2 steps) + normalize + store
        float mv = ms, lv = ls;
        mv = fmaxf(mv, __shfl_xor(mv, 16, 64)); lv += __shfl_xor(lv, 16, 64);
        mv = fmaxf(mv, __shfl_xor(mv, 32, 64)); lv += __shfl_xor(lv, 32, 64);
        const float inv = 1.f / (__expf(mv) + lv);   // inv for q = q0 + l16

        #pragma unroll
        for (int r = 0; r < 4; r++) {
            const float ir = __shfl(inv, quad * 4 + r, 64);
            const int row = q0 + quad * 4 + r;
            const size_t base = (size_t)(b * S_ + row) * D_ + h * HD_ + l16;
            ao[base]      = f2b(o[0][r] * ir);
            ao[base + 16] = f2b(o[1][r] * ir);
            ao[base + 32] = f2b(o[2][r] * ir);
            ao[base + 48] = f2b(o[3][r] * ir);
        }
    }
}

// ---------------------------------------------------------------------------
// Residual + LayerNorm over (ya [+ yb] + res); optional bf16 secondary out.
// ---------------------------------------------------------------------------
__global__ __launch_bounds__(256) void ln_kernel(
    const float* __restrict__ ya, const float* __restrict__ yb,
    const float* __restrict__ res,
    const float* __restrict__ g, const float* __restrict__ beta,
    float* __restrict__ out, unsigned short* __restrict__ outB)
{
    const int row = blockIdx.x;
    const int tid = threadIdx.x;
    const float* yr = ya + (size_t)row * D_;
    const float* y2 = yb ? yb + (size_t)row * D_ : nullptr;
    const float* rr = res + (size_t)row * D_;

    float t[4];
    float sum = 0.f, sumsq = 0.f;
    #pragma unroll
    for (int i = 0; i < 4; i++) {
        int c = tid + 256 * i;
        t[i] = yr[c] + rr[c] + (y2 ? y2[c] : 0.f);
        sum += t[i]; sumsq += t[i] * t[i];
    }
    #pragma unroll
    for (int off = 32; off >= 1; off >>= 1) {
        sum   += __shfl_xor(sum,   off, 64);
        sumsq += __shfl_xor(sumsq, off, 64);
    }
    __shared__ float rs_[4], rq_[4];
    int w = tid >> 6, lane = tid & 63;
    if (lane == 0) { rs_[w] = sum; rq_[w] = sumsq; }
    __syncthreads();
    float tot  = rs_[0] + rs_[1] + rs_[2] + rs_[3];
    float totq = rq_[0] + rq_[1] + rq_[2] + rq_[3];
    float mu   = tot  * (1.f / D_);
    float var  = totq * (1.f / D_) - mu * mu;
    float rstd = rsqrtf(var + 1e-5f);

    float* orow = out + (size_t)row * D_;
    #pragma unroll
    for (int i = 0; i < 4; i++) {
        int c = tid + 256 * i;
        float val = (t[i] - mu) * rstd * g[c] + beta[c];
        orow[c] = val;
        if (outB) outB[(size_t)row * D_ + c] = f2b(val);
    }
}

// ---------------------------------------------------------------------------
extern "C" void kernel_launch(void* const* d_in, const int* in_sizes, int n_in,
                              void* d_out, int out_size, void* d_ws, size_t ws_size,
                              hipStream_t stream)
{
    const float* x   = (const float*)d_in[0];
    const float* Wq  = (const float*)d_in[2];
    const float* bq  = (const float*)d_in[3];
    const float* Wk  = (const float*)d_in[4];
    const float* bk  = (const float*)d_in[5];
    const float* Wv  = (const float*)d_in[6];
    const float* bv  = (const float*)d_in[7];
    const float* Wo  = (const float*)d_in[8];
    const float* bo  = (const float*)d_in[9];
    const float* phase_bias = (const float*)d_in[10];
    const float* freqs = (const float*)d_in[11];
    const float* W1  = (const float*)d_in[12];
    const float* b1  = (const float*)d_in[13];
    const float* W2  = (const float*)d_in[14];
    const float* b2  = (const float*)d_in[15];
    const float* g1  = (const float*)d_in[16];
    const float* be1 = (const float*)d_in[17];
    const float* g2  = (const float*)d_in[18];
    const float* be2 = (const float*)d_in[19];
    float* out = (float*)d_out;

    char* base = (char*)d_ws;
    const size_t MiB = 1024 * 1024;
    unsigned short* WqkvT = (unsigned short*)(base);             // [0,6)
    unsigned short* WoT   = (unsigned short*)(base + 6  * MiB);  // [6,8)
    unsigned short* W1T   = (unsigned short*)(base + 8  * MiB);  // [8,16)
    unsigned short* W2T   = (unsigned short*)(base + 16 * MiB);  // [16,24)
    float*          bqkv  = (float*)(base + 24 * MiB);           // [24,25)
    unsigned short* xb    = (unsigned short*)(base + 25 * MiB);  // [25,33)
    unsigned short* qkvb  = (unsigned short*)(base + 33 * MiB);  // [33,57)
    unsigned short* qpb   = (unsigned short*)(base + 57 * MiB);  // [57,73)
    unsigned short* kpb   = (unsigned short*)(base + 73 * MiB);  // [73,89)
    unsigned short* vtb   = (unsigned short*)(base + 89 * MiB);  // [89,97)
    float*          po    = (float*)(base + 89 * MiB);           // [89,121) 2 slices (vtb dead)
    float*          x1    = (float*)(base + 121 * MiB);          // [121,137)
    unsigned short* aob   = xb;                                  // xb dead after QKV gemm
    unsigned short* x1b   = xb;                                  // aob dead after Wo gemm
    unsigned short* hb    = qkvb;                                // [33,65): qkvb+qpb dead
    float*          fo    = po;                                  // po dead after LN1

    dim3 blk(256);

    // prep
    conv_bf16_kernel<<<dim3(M_ * D_ / 256), blk, 0, stream>>>(x, xb);
    wtrans_kernel<<<dim3(32, 32), blk, 0, stream>>>(Wq, WqkvT, D_, D_);
    wtrans_kernel<<<dim3(32, 32), blk, 0, stream>>>(Wk, WqkvT + (size_t)1024 * 1024, D_, D_);
    wtrans_kernel<<<dim3(32, 32), blk, 0, stream>>>(Wv, WqkvT + (size_t)2048 * 1024, D_, D_);
    wtrans_kernel<<<dim3(32, 32), blk, 0, stream>>>(Wo, WoT, D_, D_);
    wtrans_kernel<<<dim3(DFF_ / 32, D_ / 32), blk, 0, stream>>>(W1, W1T, D_, DFF_);
    wtrans_kernel<<<dim3(D_ / 32, DFF_ / 32), blk, 0, stream>>>(W2, W2T, DFF_, D_);
    bcat_kernel<<<dim3(12), blk, 0, stream>>>(bq, bk, bv, bqkv);

    // fused QKV projection -> bf16 qkvb
    gemm_bf16_kernel<<<dim3(3072 / 128, M_ / 128, 1), blk, 0, stream>>>(
        xb, WqkvT, bqkv, nullptr, qkvb, M_, D_, D_, 3072, 0);

    // PoPE + V transpose
    pope_kernel<<<dim3(B_ * H_ * S_ * HD_ / 256), blk, 0, stream>>>(
        qkvb, phase_bias, freqs, qpb, kpb);
    vtrans_kernel<<<dim3(S_ / 64, B_ * H_), blk, 0, stream>>>(qkvb, vtb);

    // Flash attention (lazy softmax1, 128-row blocks, dbuf staging)
    attn_mfma_kernel<<<dim3(8, B_ * H_), dim3(512), 0, stream>>>(qpb, kpb, vtb, aob);

    // Output projection (split-K=2) + LN1
    gemm_bf16_kernel<<<dim3(D_ / 128, M_ / 128, 2), blk, 0, stream>>>(
        aob, WoT, bo, po, nullptr, M_, D_ / 2, D_, D_, 0);
    ln_kernel<<<dim3(M_), blk, 0, stream>>>(po, po + (size_t)M_ * D_, x, g1, be1, x1, x1b);

    // FFN
    gemm_bf16_kernel<<<dim3(DFF_ / 128, M_ / 128, 1), blk, 0, stream>>>(
        x1b, W1T, b1, nullptr, hb, M_, D_, D_, DFF_, 1);
    gemm_bf16_kernel<<<dim3(D_ / 128, M_ / 128, 2), blk, 0, stream>>>(
        hb, W2T, b2, fo, nullptr, M_, DFF_ / 2, DFF_, D_, 0);
    ln_kernel<<<dim3(M_), blk, 0, stream>>>(fo, fo + (size_t)M_ * D_, x1, g2, be2, out, nullptr);
}

// Round 8
// 417.157 us; speedup vs baseline: 1.9914x; 1.0233x over previous
//
#include <hip/hip_runtime.h>
#include <hip/hip_bf16.h>
#include <math.h>

#define B_   2
#define S_   2048
#define D_   1024
#define H_   16
#define HD_  64
#define DFF_ 4096
#define M_   (B_*S_)   // 4096 rows
#define SCALE_ 0.08838834764831845f  // 1/sqrt(128)

typedef __attribute__((ext_vector_type(8))) short bf16x8;
typedef __attribute__((ext_vector_type(4))) float f32x4;

#define MFMA16(a,b,c) __builtin_amdgcn_mfma_f32_16x16x32_bf16((a),(b),(c),0,0,0)

__device__ __forceinline__ unsigned short f2b(float f) {
    union { float f; unsigned u; } v; v.f = f;
    return (unsigned short)((v.u + 0x7FFFu + ((v.u >> 16) & 1u)) >> 16);
}
__device__ __forceinline__ float b2f(unsigned short s) {
    union { unsigned u; float f; } v; v.u = ((unsigned)s) << 16;
    return v.f;
}
// pack two f32 -> two bf16 (truncating) in ONE v_perm_b32: low short = a, high = b
__device__ __forceinline__ unsigned pk2bf(float a, float b) {
    union { float f; unsigned u; } ua, ub; ua.f = a; ub.f = b;
    return __builtin_amdgcn_perm(ub.u, ua.u, 0x07060302u);
}
__device__ __forceinline__ float softplus_f(float x) {
    return fmaxf(x, 0.f) + log1pf(__expf(-fabsf(x)));
}
// async global->LDS, 16B per lane. LDS dest = base + lane*16 (wave-uniform base).
__device__ __forceinline__ void g2l16(const void* g, void* l) {
    __builtin_amdgcn_global_load_lds(
        (const __attribute__((address_space(1))) unsigned int*)g,
        (__attribute__((address_space(3))) unsigned int*)l, 16, 0, 0);
}

// ---------------------------------------------------------------------------
__global__ __launch_bounds__(256) void conv_bf16_kernel(
    const float* __restrict__ in, unsigned short* __restrict__ out)
{
    int i = blockIdx.x * 256 + threadIdx.x;
    out[i] = f2b(in[i]);
}

// ---------------------------------------------------------------------------
// Weight transpose + bf16: W[K][N] fp32 -> WT[N][K] bf16
// ---------------------------------------------------------------------------
__global__ __launch_bounds__(256) void wtrans_kernel(
    const float* __restrict__ W, unsigned short* __restrict__ WT, int K, int N)
{
    __shared__ float tile[32][33];
    const int n0 = blockIdx.x * 32, k0 = blockIdx.y * 32;
    const int tx = threadIdx.x & 31, ty = threadIdx.x >> 5;  // ty 0..7
    #pragma unroll
    for (int i = 0; i < 4; i++)
        tile[ty + 8*i][tx] = W[(size_t)(k0 + ty + 8*i) * N + n0 + tx];
    __syncthreads();
    #pragma unroll
    for (int i = 0; i < 4; i++)
        WT[(size_t)(n0 + ty + 8*i) * K + k0 + tx] = f2b(tile[tx][ty + 8*i]);
}

// ---------------------------------------------------------------------------
__global__ __launch_bounds__(256) void bcat_kernel(
    const float* __restrict__ a, const float* __restrict__ b,
    const float* __restrict__ c, float* __restrict__ o)
{
    int i = blockIdx.x * 256 + threadIdx.x;
    o[i] = (i < 1024) ? a[i] : (i < 2048 ? b[i - 1024] : c[i - 2048]);
}

// ---------------------------------------------------------------------------
// bf16 GEMM, BK=64, XOR-swizzled LDS (conflict-free ds_read_b128), optional
// split-K (gridDim.z). C[M,N] = A[M,lda] @ WT[N,lda]^T (+bias on z=0), relu.
// 128x128 tile, 4 waves (2x2) each 64x64.
// ---------------------------------------------------------------------------
__global__ __launch_bounds__(256) void gemm_bf16_kernel(
    const unsigned short* __restrict__ A,
    const unsigned short* __restrict__ WT,
    const float* __restrict__ bias,
    float* __restrict__ outF, unsigned short* __restrict__ outB,
    int M, int Kslice, int lda, int N, int relu)
{
    __shared__ unsigned short As[128 * 64];
    __shared__ unsigned short Bs[128 * 64];

    const int tid = threadIdx.x;
    const int w = tid >> 6, lane = tid & 63;
    const int quad = lane >> 4, l16 = lane & 15;
    const size_t m0 = (size_t)blockIdx.y * 128, n0 = (size_t)blockIdx.x * 128;
    const int wm = (w >> 1) * 64, wn = (w & 1) * 64;
    const int koff = blockIdx.z * Kslice;

    const int srow = lane >> 3;                       // 0..7 row within group
    const int sc   = ((lane & 7) ^ srow) * 8;         // swizzled global chunk
    const unsigned short* ga = A  + (m0 + w * 32 + srow) * (size_t)lda + koff + sc;
    const unsigned short* gb = WT + (n0 + w * 32 + srow) * (size_t)lda + koff + sc;
    const size_t rows8 = (size_t)8 * lda;

    f32x4 acc[4][4] = {};

    for (int k0 = 0; k0 < Kslice; k0 += 64) {
        #pragma unroll
        for (int j = 0; j < 4; j++)
            g2l16(ga + j * rows8 + k0, &As[(w * 32 + j * 8) * 64]);
        #pragma unroll
        for (int j = 0; j < 4; j++)
            g2l16(gb + j * rows8 + k0, &Bs[(w * 32 + j * 8) * 64]);
        __syncthreads();

        #pragma unroll
        for (int kk = 0; kk < 2; kk++) {
            bf16x8 af[4], bfr[4];
            #pragma unroll
            for (int t = 0; t < 4; t++) {
                const int slot = ((kk * 4 + quad) ^ (l16 & 7)) * 8;
                af[t]  = *(const bf16x8*)&As[(wm + t * 16 + l16) * 64 + slot];
                bfr[t] = *(const bf16x8*)&Bs[(wn + t * 16 + l16) * 64 + slot];
            }
            #pragma unroll
            for (int mt = 0; mt < 4; mt++)
                #pragma unroll
                for (int nt = 0; nt < 4; nt++)
                    acc[mt][nt] = MFMA16(af[mt], bfr[nt], acc[mt][nt]);
        }
        __syncthreads();
    }

    float bv[4];
    #pragma unroll
    for (int nt = 0; nt < 4; nt++)
        bv[nt] = (blockIdx.z == 0) ? bias[n0 + wn + nt * 16 + l16] : 0.f;

    float* outFz = outF ? outF + (size_t)blockIdx.z * M * N : nullptr;

    #pragma unroll
    for (int mt = 0; mt < 4; mt++) {
        #pragma unroll
        for (int nt = 0; nt < 4; nt++) {
            const size_t n = n0 + wn + nt * 16 + l16;
            #pragma unroll
            for (int r = 0; r < 4; r++) {
                const size_t m = m0 + wm + mt * 16 + quad * 4 + r;
                float val = acc[mt][nt][r] + bv[nt];
                if (relu) val = fmaxf(val, 0.f);
                const size_t idx = m * N + n;
                if (outFz) outFz[idx] = val;
                if (outB) outB[idx] = f2b(val);
            }
        }
    }
}

// ---------------------------------------------------------------------------
// PoPE: qkvb bf16 (B,S,3072) -> bf16 qp,kp (B*H, S, 128). Q pre-scaled.
// ---------------------------------------------------------------------------
__global__ __launch_bounds__(256) void pope_kernel(
    const unsigned short* __restrict__ qkv,
    const float* __restrict__ phase_bias, const float* __restrict__ freqs,
    unsigned short* __restrict__ qp, unsigned short* __restrict__ kp)
{
    int idx = blockIdx.x * 256 + threadIdx.x;   // over B*H*S*HD = 4M
    int d = idx & 63;
    int s = (idx >> 6) & (S_ - 1);
    int h = (idx >> 17) & (H_ - 1);
    int b = idx >> 21;

    size_t src = (size_t)(b * S_ + s) * 3072 + h * HD_ + d;
    float muq = softplus_f(b2f(qkv[src])) * SCALE_;
    float muk = softplus_f(b2f(qkv[src + 1024]));

    float ph = (float)s * freqs[d] + phase_bias[h * HD_ + d];
    float sn, cs;
    sincosf(ph, &sn, &cs);

    size_t o = ((size_t)(b * H_ + h) * S_ + s) * 128 + d;
    qp[o]      = f2b(muq * cs);
    qp[o + 64] = f2b(muq * sn);
    kp[o]      = f2b(muk * cs);
    kp[o + 64] = f2b(muk * sn);
}

// ---------------------------------------------------------------------------
// V transpose: qkvb bf16 (B,S,3072) col 2048.. -> vt bf16 (B*H, 64, S)
// ---------------------------------------------------------------------------
__global__ __launch_bounds__(256) void vtrans_kernel(
    const unsigned short* __restrict__ qkv, unsigned short* __restrict__ vt)
{
    __shared__ unsigned short tile[64][72];
    const int bh = blockIdx.y, b = bh >> 4, h = bh & 15;
    const int s0 = blockIdx.x * 64;
    const int tid = threadIdx.x;
    #pragma unroll
    for (int i = 0; i < 16; i++) {
        int idx = i * 256 + tid;
        int s = idx >> 6, d = idx & 63;
        tile[s][d] = qkv[(size_t)(b * S_ + s0 + s) * 3072 + 2048 + h * HD_ + d];
    }
    __syncthreads();
    #pragma unroll
    for (int i = 0; i < 16; i++) {
        int idx = i * 256 + tid;
        int d = idx >> 6, s = idx & 63;
        vt[((size_t)bh * 64 + d) * S_ + s0 + s] = tile[s][d];
    }
}

// ---------------------------------------------------------------------------
// MFMA flash attention, softmax1, lazy normalization, S^T trick.
// 128 q rows per block (8 waves x 16). K/V double-buffered staging.
// Causal split over grid.z: z=0 -> part a=15-x (big, dispatched first),
// z=1 -> part a=x (small). 512 blocks -> 2 blocks/CU (16 waves/CU).
// ---------------------------------------------------------------------------
__global__ __launch_bounds__(512, 4) void attn_mfma_kernel(
    const unsigned short* __restrict__ qp,
    const unsigned short* __restrict__ kp,
    const unsigned short* __restrict__ vt,
    unsigned short* __restrict__ ao)
{
    __shared__ unsigned short kt_lds[2][64][128];  // [buf][key][k], chunk^=(key&15)
    __shared__ unsigned short vt_lds[2][64][64];   // [buf][d][key], chunk^=(d&7)
    __shared__ unsigned short p_lds[8][16][72];    // per-wave P: [q][key]

    const int tid = threadIdx.x;
    const int w = tid >> 6, lane = tid & 63;
    const int quad = lane >> 4, l16 = lane & 15;
    const int bh = blockIdx.y, b = bh >> 4, h = bh & 15;

    const int a = (blockIdx.z == 0) ? 15 - (int)blockIdx.x : (int)blockIdx.x;
    const int q0b = a * 128;
    const int q0 = q0b + w * 16;

    const unsigned short* qbase = qp + ((size_t)bh * S_ + q0 + l16) * 128 + quad * 8;
    bf16x8 qa[4];
    #pragma unroll
    for (int kc = 0; kc < 4; kc++) qa[kc] = *(const bf16x8*)(qbase + kc * 32);

    // hoisted staging base pointers
    const int krow = lane >> 4, kslot = lane & 15;   // K: 4 rows/instr
    const int vrow = lane >> 3, vslot = lane & 7;    // V: 8 rows/instr
    const int kr0 = w * 8 + krow,     kc0 = kslot ^ (kr0 & 15);
    const int kr1 = w * 8 + 4 + krow, kc1 = kslot ^ (kr1 & 15);
    const int vd  = w * 8 + vrow,     vc  = vslot ^ (vd & 7);
    const unsigned short* kg0 = kp + ((size_t)bh * S_ + kr0) * 128 + kc0 * 8;
    const unsigned short* kg1 = kp + ((size_t)bh * S_ + kr1) * 128 + kc1 * 8;
    const unsigned short* vg0 = vt + ((size_t)bh * 64 + vd) * S_ + vc * 8;

    f32x4 o[4] = {};
    float ms = -1e30f, ls = 0.f;

    const int ntiles = 2 * a + 2;

    // stage tile 0 -> buf 0
    g2l16(kg0, &kt_lds[0][w * 8][0]);
    g2l16(kg1, &kt_lds[0][w * 8 + 4][0]);
    g2l16(vg0, &vt_lds[0][w * 8][0]);

    for (int ti = 0; ti < ntiles; ti++) {
        const int t0 = ti * 64;
        __syncthreads();   // drains this tile's staging; frees other buf
        if (ti + 1 < ntiles) {
            const int nb = (ti + 1) & 1;
            const size_t ko = (size_t)(ti + 1) * (64 * 128);
            const size_t vo = (size_t)(ti + 1) * 64;
            g2l16(kg0 + ko, &kt_lds[nb][w * 8][0]);
            g2l16(kg1 + ko, &kt_lds[nb][w * 8 + 4][0]);
            g2l16(vg0 + vo, &vt_lds[nb][w * 8][0]);
        }
        const int buf = ti & 1;

        if (t0 <= q0 + 15) {   // wave-uniform causal skip
            // QK^T transposed: A = K-frag (rows=keys), B = Q-frag
            f32x4 sf[4];
            #pragma unroll
            for (int kg = 0; kg < 4; kg++) {
                f32x4 s = {0, 0, 0, 0};
                const int row = kg * 16 + l16;
                #pragma unroll
                for (int kc = 0; kc < 4; kc++) {
                    const int slot = (kc * 4 + quad) ^ l16;
                    s = MFMA16(*(const bf16x8*)&kt_lds[buf][row][slot * 8], qa[kc], s);
                }
                sf[kg] = s;   // sf[kg][r] = score(key=t0+kg*16+quad*4+r, q=q0+l16)
            }

            // mask (diagonal tiles only) + exp + packed P store
            const int qrow = q0 + l16;
            const bool dmask = (t0 + 63 > q0);
            #pragma unroll
            for (int kg = 0; kg < 4; kg++) {
                const int kbase = t0 + kg * 16 + quad * 4;
                float v0 = sf[kg][0], v1 = sf[kg][1], v2 = sf[kg][2], v3 = sf[kg][3];
                if (dmask) {
                    v0 = (kbase     <= qrow) ? v0 : -1e30f;
                    v1 = (kbase + 1 <= qrow) ? v1 : -1e30f;
                    v2 = (kbase + 2 <= qrow) ? v2 : -1e30f;
                    v3 = (kbase + 3 <= qrow) ? v3 : -1e30f;
                }
                ms = fmaxf(ms, fmaxf(fmaxf(v0, v1), fmaxf(v2, v3)));
                const float e0 = __expf(v0), e1 = __expf(v1);
                const float e2 = __expf(v2), e3 = __expf(v3);
                ls += (e0 + e1) + (e2 + e3);
                uint2 pk;
                pk.x = pk2bf(e0, e1);
                pk.y = pk2bf(e2, e3);
                *(uint2*)&p_lds[w][l16][kg * 16 + quad * 4] = pk;
            }
            asm volatile("s_waitcnt lgkmcnt(0)" ::: "memory");
            bf16x8 pa0 = *(const bf16x8*)&p_lds[w][l16][quad * 8];
            bf16x8 pa1 = *(const bf16x8*)&p_lds[w][l16][quad * 8 + 32];

            // PV
            #pragma unroll
            for (int dg = 0; dg < 4; dg++) {
                const int row = dg * 16 + l16;
                const int s0_ = quad ^ (l16 & 7);
                const int s1_ = (quad + 4) ^ (l16 & 7);
                o[dg] = MFMA16(pa0, *(const bf16x8*)&vt_lds[buf][row][s0_ * 8], o[dg]);
                o[dg] = MFMA16(pa1, *(const bf16x8*)&vt_lds[buf][row][s1_ * 8], o[dg]);
            }
        }
    }

    // cross-quad reduction (2 steps) + normalize + store
    float mv = ms, lv = ls;
    mv = fmaxf(mv, __shfl_xor(mv, 16, 64)); lv += __shfl_xor(lv, 16, 64);
    mv = fmaxf(mv, __shfl_xor(mv, 32, 64)); lv += __shfl_xor(lv, 32, 64);
    const float inv = 1.f / (__expf(mv) + lv);   // for q = q0 + l16

    #pragma unroll
    for (int r = 0; r < 4; r++) {
        const float ir = __shfl(inv, quad * 4 + r, 64);
        const int row = q0 + quad * 4 + r;
        const size_t base = (size_t)(b * S_ + row) * D_ + h * HD_ + l16;
        ao[base]      = f2b(o[0][r] * ir);
        ao[base + 16] = f2b(o[1][r] * ir);
        ao[base + 32] = f2b(o[2][r] * ir);
        ao[base + 48] = f2b(o[3][r] * ir);
    }
}

// ---------------------------------------------------------------------------
// Residual + LayerNorm over (ya [+ yb] + res); optional bf16 secondary out.
// ---------------------------------------------------------------------------
__global__ __launch_bounds__(256) void ln_kernel(
    const float* __restrict__ ya, const float* __restrict__ yb,
    const float* __restrict__ res,
    const float* __restrict__ g, const float* __restrict__ beta,
    float* __restrict__ out, unsigned short* __restrict__ outB)
{
    const int row = blockIdx.x;
    const int tid = threadIdx.x;
    const float* yr = ya + (size_t)row * D_;
    const float* y2 = yb ? yb + (size_t)row * D_ : nullptr;
    const float* rr = res + (size_t)row * D_;

    float t[4];
    float sum = 0.f, sumsq = 0.f;
    #pragma unroll
    for (int i = 0; i < 4; i++) {
        int c = tid + 256 * i;
        t[i] = yr[c] + rr[c] + (y2 ? y2[c] : 0.f);
        sum += t[i]; sumsq += t[i] * t[i];
    }
    #pragma unroll
    for (int off = 32; off >= 1; off >>= 1) {
        sum   += __shfl_xor(sum,   off, 64);
        sumsq += __shfl_xor(sumsq, off, 64);
    }
    __shared__ float rs_[4], rq_[4];
    int w = tid >> 6, lane = tid & 63;
    if (lane == 0) { rs_[w] = sum; rq_[w] = sumsq; }
    __syncthreads();
    float tot  = rs_[0] + rs_[1] + rs_[2] + rs_[3];
    float totq = rq_[0] + rq_[1] + rq_[2] + rq_[3];
    float mu   = tot  * (1.f / D_);
    float var  = totq * (1.f / D_) - mu * mu;
    float rstd = rsqrtf(var + 1e-5f);

    float* orow = out + (size_t)row * D_;
    #pragma unroll
    for (int i = 0; i < 4; i++) {
        int c = tid + 256 * i;
        float val = (t[i] - mu) * rstd * g[c] + beta[c];
        orow[c] = val;
        if (outB) outB[(size_t)row * D_ + c] = f2b(val);
    }
}

// ---------------------------------------------------------------------------
extern "C" void kernel_launch(void* const* d_in, const int* in_sizes, int n_in,
                              void* d_out, int out_size, void* d_ws, size_t ws_size,
                              hipStream_t stream)
{
    const float* x   = (const float*)d_in[0];
    const float* Wq  = (const float*)d_in[2];
    const float* bq  = (const float*)d_in[3];
    const float* Wk  = (const float*)d_in[4];
    const float* bk  = (const float*)d_in[5];
    const float* Wv  = (const float*)d_in[6];
    const float* bv  = (const float*)d_in[7];
    const float* Wo  = (const float*)d_in[8];
    const float* bo  = (const float*)d_in[9];
    const float* phase_bias = (const float*)d_in[10];
    const float* freqs = (const float*)d_in[11];
    const float* W1  = (const float*)d_in[12];
    const float* b1  = (const float*)d_in[13];
    const float* W2  = (const float*)d_in[14];
    const float* b2  = (const float*)d_in[15];
    const float* g1  = (const float*)d_in[16];
    const float* be1 = (const float*)d_in[17];
    const float* g2  = (const float*)d_in[18];
    const float* be2 = (const float*)d_in[19];
    float* out = (float*)d_out;

    char* base = (char*)d_ws;
    const size_t MiB = 1024 * 1024;
    unsigned short* WqkvT = (unsigned short*)(base);             // [0,6)
    unsigned short* WoT   = (unsigned short*)(base + 6  * MiB);  // [6,8)
    unsigned short* W1T   = (unsigned short*)(base + 8  * MiB);  // [8,16)
    unsigned short* W2T   = (unsigned short*)(base + 16 * MiB);  // [16,24)
    float*          bqkv  = (float*)(base + 24 * MiB);           // [24,25)
    unsigned short* xb    = (unsigned short*)(base + 25 * MiB);  // [25,33)
    unsigned short* qkvb  = (unsigned short*)(base + 33 * MiB);  // [33,57)
    unsigned short* qpb   = (unsigned short*)(base + 57 * MiB);  // [57,73)
    unsigned short* kpb   = (unsigned short*)(base + 73 * MiB);  // [73,89)
    unsigned short* vtb   = (unsigned short*)(base + 89 * MiB);  // [89,97)
    float*          po    = (float*)(base + 89 * MiB);           // [89,121) 2 slices (vtb dead)
    float*          x1    = (float*)(base + 121 * MiB);          // [121,137)
    unsigned short* aob   = xb;                                  // xb dead after QKV gemm
    unsigned short* x1b   = xb;                                  // aob dead after Wo gemm
    unsigned short* hb    = qkvb;                                // [33,65): qkvb+qpb dead
    float*          fo    = po;                                  // po dead after LN1

    dim3 blk(256);

    // prep
    conv_bf16_kernel<<<dim3(M_ * D_ / 256), blk, 0, stream>>>(x, xb);
    wtrans_kernel<<<dim3(32, 32), blk, 0, stream>>>(Wq, WqkvT, D_, D_);
    wtrans_kernel<<<dim3(32, 32), blk, 0, stream>>>(Wk, WqkvT + (size_t)1024 * 1024, D_, D_);
    wtrans_kernel<<<dim3(32, 32), blk, 0, stream>>>(Wv, WqkvT + (size_t)2048 * 1024, D_, D_);
    wtrans_kernel<<<dim3(32, 32), blk, 0, stream>>>(Wo, WoT, D_, D_);
    wtrans_kernel<<<dim3(DFF_ / 32, D_ / 32), blk, 0, stream>>>(W1, W1T, D_, DFF_);
    wtrans_kernel<<<dim3(D_ / 32, DFF_ / 32), blk, 0, stream>>>(W2, W2T, DFF_, D_);
    bcat_kernel<<<dim3(12), blk, 0, stream>>>(bq, bk, bv, bqkv);

    // fused QKV projection -> bf16 qkvb
    gemm_bf16_kernel<<<dim3(3072 / 128, M_ / 128, 1), blk, 0, stream>>>(
        xb, WqkvT, bqkv, nullptr, qkvb, M_, D_, D_, 3072, 0);

    // PoPE + V transpose
    pope_kernel<<<dim3(B_ * H_ * S_ * HD_ / 256), blk, 0, stream>>>(
        qkvb, phase_bias, freqs, qpb, kpb);
    vtrans_kernel<<<dim3(S_ / 64, B_ * H_), blk, 0, stream>>>(qkvb, vtb);

    // Flash attention (lazy softmax1, 128-row blocks, dbuf, 2 blocks/CU)
    attn_mfma_kernel<<<dim3(8, B_ * H_, 2), dim3(512), 0, stream>>>(qpb, kpb, vtb, aob);

    // Output projection (split-K=2) + LN1
    gemm_bf16_kernel<<<dim3(D_ / 128, M_ / 128, 2), blk, 0, stream>>>(
        aob, WoT, bo, po, nullptr, M_, D_ / 2, D_, D_, 0);
    ln_kernel<<<dim3(M_), blk, 0, stream>>>(po, po + (size_t)M_ * D_, x, g1, be1, x1, x1b);

    // FFN
    gemm_bf16_kernel<<<dim3(DFF_ / 128, M_ / 128, 1), blk, 0, stream>>>(
        x1b, W1T, b1, nullptr, hb, M_, D_, D_, DFF_, 1);
    gemm_bf16_kernel<<<dim3(D_ / 128, M_ / 128, 2), blk, 0, stream>>>(
        hb, W2T, b2, fo, nullptr, M_, DFF_ / 2, DFF_, D_, 0);
    ln_kernel<<<dim3(M_), blk, 0, stream>>>(fo, fo + (size_t)M_ * D_, x1, g2, be2, out, nullptr);
}

// Round 9
// 401.917 us; speedup vs baseline: 2.0669x; 1.0379x over previous
//
#include <hip/hip_runtime.h>
#include <hip/hip_bf16.h>
#include <math.h>

#define B_   2
#define S_   2048
#define D_   1024
#define H_   16
#define HD_  64
#define DFF_ 4096
#define M_   (B_*S_)   // 4096 rows
#define SCALE_ 0.08838834764831845f  // 1/sqrt(128)

typedef __attribute__((ext_vector_type(8))) short bf16x8;
typedef __attribute__((ext_vector_type(4))) float f32x4;

#define MFMA16(a,b,c) __builtin_amdgcn_mfma_f32_16x16x32_bf16((a),(b),(c),0,0,0)

__device__ __forceinline__ unsigned short f2b(float f) {
    union { float f; unsigned u; } v; v.f = f;
    return (unsigned short)((v.u + 0x7FFFu + ((v.u >> 16) & 1u)) >> 16);
}
__device__ __forceinline__ float b2f(unsigned short s) {
    union { unsigned u; float f; } v; v.u = ((unsigned)s) << 16;
    return v.f;
}
// pack two f32 -> two bf16 (truncating) in ONE v_perm_b32
__device__ __forceinline__ unsigned pk2bf(float a, float b) {
    union { float f; unsigned u; } ua, ub; ua.f = a; ub.f = b;
    return __builtin_amdgcn_perm(ub.u, ua.u, 0x07060302u);
}
__device__ __forceinline__ float softplus_f(float x) {
    return fmaxf(x, 0.f) + log1pf(__expf(-fabsf(x)));
}
// async global->LDS, 16B per lane. LDS dest = base + lane*16 (wave-uniform base).
__device__ __forceinline__ void g2l16(const void* g, void* l) {
    __builtin_amdgcn_global_load_lds(
        (const __attribute__((address_space(1))) unsigned int*)g,
        (__attribute__((address_space(3))) unsigned int*)l, 16, 0, 0);
}

// ---------------------------------------------------------------------------
__global__ __launch_bounds__(256) void conv_bf16_kernel(
    const float* __restrict__ in, unsigned short* __restrict__ out)
{
    int i = (blockIdx.x * 256 + threadIdx.x) * 4;
    float4 v = *(const float4*)&in[i];
    ushort4 o;
    o.x = f2b(v.x); o.y = f2b(v.y); o.z = f2b(v.z); o.w = f2b(v.w);
    *(ushort4*)&out[i] = o;
}

// ---------------------------------------------------------------------------
// Weight transpose + bf16: W[K][N] fp32 -> WT[N][K] bf16
// ---------------------------------------------------------------------------
__global__ __launch_bounds__(256) void wtrans_kernel(
    const float* __restrict__ W, unsigned short* __restrict__ WT, int K, int N)
{
    __shared__ float tile[32][33];
    const int n0 = blockIdx.x * 32, k0 = blockIdx.y * 32;
    const int tx = threadIdx.x & 31, ty = threadIdx.x >> 5;  // ty 0..7
    #pragma unroll
    for (int i = 0; i < 4; i++)
        tile[ty + 8*i][tx] = W[(size_t)(k0 + ty + 8*i) * N + n0 + tx];
    __syncthreads();
    #pragma unroll
    for (int i = 0; i < 4; i++)
        WT[(size_t)(n0 + ty + 8*i) * K + k0 + tx] = f2b(tile[tx][ty + 8*i]);
}

// ---------------------------------------------------------------------------
__global__ __launch_bounds__(256) void bcat_kernel(
    const float* __restrict__ a, const float* __restrict__ b,
    const float* __restrict__ c, float* __restrict__ o)
{
    int i = blockIdx.x * 256 + threadIdx.x;
    o[i] = (i < 1024) ? a[i] : (i < 2048 ? b[i - 1024] : c[i - 2048]);
}

// ---------------------------------------------------------------------------
// bf16 GEMM, BK=64, XOR-swizzled LDS, DOUBLE-BUFFERED staging (one barrier
// per K-iter; prefetch overlaps compute), XCD-aware block remap (lin%8 = XCD,
// each XCD gets a contiguous m-major id range -> A panel resident in its L2).
// Optional split-K via gridDim.z. C[M,N]=A[M,lda]@WT[N,lda]^T (+bias z=0).
// ---------------------------------------------------------------------------
__global__ __launch_bounds__(256) void gemm_bf16_kernel(
    const unsigned short* __restrict__ A,
    const unsigned short* __restrict__ WT,
    const float* __restrict__ bias,
    float* __restrict__ outF, unsigned short* __restrict__ outB,
    int M, int Kslice, int lda, int N, int relu)
{
    __shared__ unsigned short As[2][128 * 64];
    __shared__ unsigned short Bs[2][128 * 64];

    const int tid = threadIdx.x;
    const int w = tid >> 6, lane = tid & 63;
    const int quad = lane >> 4, l16 = lane & 15;

    // XCD-aware remap (total blocks divisible by 8)
    const int nn = gridDim.x, nm = gridDim.y;
    const int lin = ((int)blockIdx.z * nm + (int)blockIdx.y) * nn + (int)blockIdx.x;
    const int per = (nn * nm * (int)gridDim.z) >> 3;
    const int id  = (lin & 7) * per + (lin >> 3);
    const int zz  = id / (nn * nm);
    const int rem = id - zz * nn * nm;
    const int mt_ = rem / nn, nt_ = rem - mt_ * nn;

    const size_t m0 = (size_t)mt_ * 128, n0 = (size_t)nt_ * 128;
    const int wm = (w >> 1) * 64, wn = (w & 1) * 64;
    const int koff = zz * Kslice;

    const int srow = lane >> 3;                       // 0..7 row within group
    const int sc   = ((lane & 7) ^ srow) * 8;         // swizzled global chunk
    const unsigned short* ga = A  + (m0 + w * 32 + srow) * (size_t)lda + koff + sc;
    const unsigned short* gb = WT + (n0 + w * 32 + srow) * (size_t)lda + koff + sc;
    const size_t rows8 = (size_t)8 * lda;

    f32x4 acc[4][4] = {};
    const int niter = Kslice >> 6;

    // stage iter 0 -> buf 0
    #pragma unroll
    for (int j = 0; j < 4; j++) g2l16(ga + j * rows8, &As[0][(w * 32 + j * 8) * 64]);
    #pragma unroll
    for (int j = 0; j < 4; j++) g2l16(gb + j * rows8, &Bs[0][(w * 32 + j * 8) * 64]);

    for (int i = 0; i < niter; i++) {
        __syncthreads();   // drains buf[i&1] staging; all waves past buf[(i+1)&1] reads
        if (i + 1 < niter) {
            const int nb = (i + 1) & 1, k0 = (i + 1) << 6;
            #pragma unroll
            for (int j = 0; j < 4; j++)
                g2l16(ga + j * rows8 + k0, &As[nb][(w * 32 + j * 8) * 64]);
            #pragma unroll
            for (int j = 0; j < 4; j++)
                g2l16(gb + j * rows8 + k0, &Bs[nb][(w * 32 + j * 8) * 64]);
        }
        const int buf = i & 1;

        #pragma unroll
        for (int kk = 0; kk < 2; kk++) {
            bf16x8 af[4], bfr[4];
            #pragma unroll
            for (int t = 0; t < 4; t++) {
                const int slot = ((kk * 4 + quad) ^ (l16 & 7)) * 8;
                af[t]  = *(const bf16x8*)&As[buf][(wm + t * 16 + l16) * 64 + slot];
                bfr[t] = *(const bf16x8*)&Bs[buf][(wn + t * 16 + l16) * 64 + slot];
            }
            #pragma unroll
            for (int mt = 0; mt < 4; mt++)
                #pragma unroll
                for (int nt = 0; nt < 4; nt++)
                    acc[mt][nt] = MFMA16(af[mt], bfr[nt], acc[mt][nt]);
        }
    }

    float bv[4];
    #pragma unroll
    for (int nt = 0; nt < 4; nt++)
        bv[nt] = (zz == 0) ? bias[n0 + wn + nt * 16 + l16] : 0.f;

    float* outFz = outF ? outF + (size_t)zz * M * N : nullptr;

    #pragma unroll
    for (int mt = 0; mt < 4; mt++) {
        #pragma unroll
        for (int nt = 0; nt < 4; nt++) {
            const size_t n = n0 + wn + nt * 16 + l16;
            #pragma unroll
            for (int r = 0; r < 4; r++) {
                const size_t m = m0 + wm + mt * 16 + quad * 4 + r;
                float val = acc[mt][nt][r] + bv[nt];
                if (relu) val = fmaxf(val, 0.f);
                const size_t idx = m * N + n;
                if (outFz) outFz[idx] = val;
                if (outB) outB[idx] = f2b(val);
            }
        }
    }
}

// ---------------------------------------------------------------------------
// PoPE: qkvb bf16 (B,S,3072) -> bf16 qp,kp (B*H, S, 128). Q pre-scaled.
// ---------------------------------------------------------------------------
__global__ __launch_bounds__(256) void pope_kernel(
    const unsigned short* __restrict__ qkv,
    const float* __restrict__ phase_bias, const float* __restrict__ freqs,
    unsigned short* __restrict__ qp, unsigned short* __restrict__ kp)
{
    int idx = blockIdx.x * 256 + threadIdx.x;   // over B*H*S*HD = 4M
    int d = idx & 63;
    int s = (idx >> 6) & (S_ - 1);
    int h = (idx >> 17) & (H_ - 1);
    int b = idx >> 21;

    size_t src = (size_t)(b * S_ + s) * 3072 + h * HD_ + d;
    float muq = softplus_f(b2f(qkv[src])) * SCALE_;
    float muk = softplus_f(b2f(qkv[src + 1024]));

    float ph = (float)s * freqs[d] + phase_bias[h * HD_ + d];
    float sn, cs;
    sincosf(ph, &sn, &cs);

    size_t o = ((size_t)(b * H_ + h) * S_ + s) * 128 + d;
    qp[o]      = f2b(muq * cs);
    qp[o + 64] = f2b(muq * sn);
    kp[o]      = f2b(muk * cs);
    kp[o + 64] = f2b(muk * sn);
}

// ---------------------------------------------------------------------------
// V transpose: qkvb bf16 (B,S,3072) col 2048.. -> vt bf16 (B*H, 64, S)
// ---------------------------------------------------------------------------
__global__ __launch_bounds__(256) void vtrans_kernel(
    const unsigned short* __restrict__ qkv, unsigned short* __restrict__ vt)
{
    __shared__ unsigned short tile[64][72];
    const int bh = blockIdx.y, b = bh >> 4, h = bh & 15;
    const int s0 = blockIdx.x * 64;
    const int tid = threadIdx.x;
    #pragma unroll
    for (int i = 0; i < 16; i++) {
        int idx = i * 256 + tid;
        int s = idx >> 6, d = idx & 63;
        tile[s][d] = qkv[(size_t)(b * S_ + s0 + s) * 3072 + 2048 + h * HD_ + d];
    }
    __syncthreads();
    #pragma unroll
    for (int i = 0; i < 16; i++) {
        int idx = i * 256 + tid;
        int d = idx >> 6, s = idx & 63;
        vt[((size_t)bh * 64 + d) * S_ + s0 + s] = tile[s][d];
    }
}

// ---------------------------------------------------------------------------
// MFMA flash attention (unchanged from R8): softmax1, lazy normalization,
// S^T trick, 128 q rows/block, dbuf K/V staging, causal split over grid.z.
// ---------------------------------------------------------------------------
__global__ __launch_bounds__(512, 4) void attn_mfma_kernel(
    const unsigned short* __restrict__ qp,
    const unsigned short* __restrict__ kp,
    const unsigned short* __restrict__ vt,
    unsigned short* __restrict__ ao)
{
    __shared__ unsigned short kt_lds[2][64][128];  // [buf][key][k], chunk^=(key&15)
    __shared__ unsigned short vt_lds[2][64][64];   // [buf][d][key], chunk^=(d&7)
    __shared__ unsigned short p_lds[8][16][72];    // per-wave P: [q][key]

    const int tid = threadIdx.x;
    const int w = tid >> 6, lane = tid & 63;
    const int quad = lane >> 4, l16 = lane & 15;
    const int bh = blockIdx.y, b = bh >> 4, h = bh & 15;

    const int a = (blockIdx.z == 0) ? 15 - (int)blockIdx.x : (int)blockIdx.x;
    const int q0b = a * 128;
    const int q0 = q0b + w * 16;

    const unsigned short* qbase = qp + ((size_t)bh * S_ + q0 + l16) * 128 + quad * 8;
    bf16x8 qa[4];
    #pragma unroll
    for (int kc = 0; kc < 4; kc++) qa[kc] = *(const bf16x8*)(qbase + kc * 32);

    const int krow = lane >> 4, kslot = lane & 15;
    const int vrow = lane >> 3, vslot = lane & 7;
    const int kr0 = w * 8 + krow,     kc0 = kslot ^ (kr0 & 15);
    const int kr1 = w * 8 + 4 + krow, kc1 = kslot ^ (kr1 & 15);
    const int vd  = w * 8 + vrow,     vc  = vslot ^ (vd & 7);
    const unsigned short* kg0 = kp + ((size_t)bh * S_ + kr0) * 128 + kc0 * 8;
    const unsigned short* kg1 = kp + ((size_t)bh * S_ + kr1) * 128 + kc1 * 8;
    const unsigned short* vg0 = vt + ((size_t)bh * 64 + vd) * S_ + vc * 8;

    f32x4 o[4] = {};
    float ms = -1e30f, ls = 0.f;

    const int ntiles = 2 * a + 2;

    g2l16(kg0, &kt_lds[0][w * 8][0]);
    g2l16(kg1, &kt_lds[0][w * 8 + 4][0]);
    g2l16(vg0, &vt_lds[0][w * 8][0]);

    for (int ti = 0; ti < ntiles; ti++) {
        const int t0 = ti * 64;
        __syncthreads();
        if (ti + 1 < ntiles) {
            const int nb = (ti + 1) & 1;
            const size_t ko = (size_t)(ti + 1) * (64 * 128);
            const size_t vo = (size_t)(ti + 1) * 64;
            g2l16(kg0 + ko, &kt_lds[nb][w * 8][0]);
            g2l16(kg1 + ko, &kt_lds[nb][w * 8 + 4][0]);
            g2l16(vg0 + vo, &vt_lds[nb][w * 8][0]);
        }
        const int buf = ti & 1;

        if (t0 <= q0 + 15) {
            f32x4 sf[4];
            #pragma unroll
            for (int kg = 0; kg < 4; kg++) {
                f32x4 s = {0, 0, 0, 0};
                const int row = kg * 16 + l16;
                #pragma unroll
                for (int kc = 0; kc < 4; kc++) {
                    const int slot = (kc * 4 + quad) ^ l16;
                    s = MFMA16(*(const bf16x8*)&kt_lds[buf][row][slot * 8], qa[kc], s);
                }
                sf[kg] = s;
            }

            const int qrow = q0 + l16;
            const bool dmask = (t0 + 63 > q0);
            #pragma unroll
            for (int kg = 0; kg < 4; kg++) {
                const int kbase = t0 + kg * 16 + quad * 4;
                float v0 = sf[kg][0], v1 = sf[kg][1], v2 = sf[kg][2], v3 = sf[kg][3];
                if (dmask) {
                    v0 = (kbase     <= qrow) ? v0 : -1e30f;
                    v1 = (kbase + 1 <= qrow) ? v1 : -1e30f;
                    v2 = (kbase + 2 <= qrow) ? v2 : -1e30f;
                    v3 = (kbase + 3 <= qrow) ? v3 : -1e30f;
                }
                ms = fmaxf(ms, fmaxf(fmaxf(v0, v1), fmaxf(v2, v3)));
                const float e0 = __expf(v0), e1 = __expf(v1);
                const float e2 = __expf(v2), e3 = __expf(v3);
                ls += (e0 + e1) + (e2 + e3);
                uint2 pk;
                pk.x = pk2bf(e0, e1);
                pk.y = pk2bf(e2, e3);
                *(uint2*)&p_lds[w][l16][kg * 16 + quad * 4] = pk;
            }
            asm volatile("s_waitcnt lgkmcnt(0)" ::: "memory");
            bf16x8 pa0 = *(const bf16x8*)&p_lds[w][l16][quad * 8];
            bf16x8 pa1 = *(const bf16x8*)&p_lds[w][l16][quad * 8 + 32];

            #pragma unroll
            for (int dg = 0; dg < 4; dg++) {
                const int row = dg * 16 + l16;
                const int s0_ = quad ^ (l16 & 7);
                const int s1_ = (quad + 4) ^ (l16 & 7);
                o[dg] = MFMA16(pa0, *(const bf16x8*)&vt_lds[buf][row][s0_ * 8], o[dg]);
                o[dg] = MFMA16(pa1, *(const bf16x8*)&vt_lds[buf][row][s1_ * 8], o[dg]);
            }
        }
    }

    float mv = ms, lv = ls;
    mv = fmaxf(mv, __shfl_xor(mv, 16, 64)); lv += __shfl_xor(lv, 16, 64);
    mv = fmaxf(mv, __shfl_xor(mv, 32, 64)); lv += __shfl_xor(lv, 32, 64);
    const float inv = 1.f / (__expf(mv) + lv);

    #pragma unroll
    for (int r = 0; r < 4; r++) {
        const float ir = __shfl(inv, quad * 4 + r, 64);
        const int row = q0 + quad * 4 + r;
        const size_t base = (size_t)(b * S_ + row) * D_ + h * HD_ + l16;
        ao[base]      = f2b(o[0][r] * ir);
        ao[base + 16] = f2b(o[1][r] * ir);
        ao[base + 32] = f2b(o[2][r] * ir);
        ao[base + 48] = f2b(o[3][r] * ir);
    }
}

// ---------------------------------------------------------------------------
// Residual + LayerNorm over (ya + yb + res); residual fp32 OR bf16;
// outputs fp32 and/or bf16 (either may be null).
// ---------------------------------------------------------------------------
__global__ __launch_bounds__(256) void ln_kernel(
    const float* __restrict__ ya, const float* __restrict__ yb,
    const float* __restrict__ resF, const unsigned short* __restrict__ resB,
    const float* __restrict__ g, const float* __restrict__ beta,
    float* __restrict__ outF, unsigned short* __restrict__ outB)
{
    const int row = blockIdx.x;
    const int tid = threadIdx.x;
    const float* yr = ya + (size_t)row * D_;
    const float* y2 = yb ? yb + (size_t)row * D_ : nullptr;

    float t[4];
    float sum = 0.f, sumsq = 0.f;
    #pragma unroll
    for (int i = 0; i < 4; i++) {
        int c = tid + 256 * i;
        float rv = resF ? resF[(size_t)row * D_ + c] : b2f(resB[(size_t)row * D_ + c]);
        t[i] = yr[c] + rv + (y2 ? y2[c] : 0.f);
        sum += t[i]; sumsq += t[i] * t[i];
    }
    #pragma unroll
    for (int off = 32; off >= 1; off >>= 1) {
        sum   += __shfl_xor(sum,   off, 64);
        sumsq += __shfl_xor(sumsq, off, 64);
    }
    __shared__ float rs_[4], rq_[4];
    int w = tid >> 6, lane = tid & 63;
    if (lane == 0) { rs_[w] = sum; rq_[w] = sumsq; }
    __syncthreads();
    float tot  = rs_[0] + rs_[1] + rs_[2] + rs_[3];
    float totq = rq_[0] + rq_[1] + rq_[2] + rq_[3];
    float mu   = tot  * (1.f / D_);
    float var  = totq * (1.f / D_) - mu * mu;
    float rstd = rsqrtf(var + 1e-5f);

    #pragma unroll
    for (int i = 0; i < 4; i++) {
        int c = tid + 256 * i;
        float val = (t[i] - mu) * rstd * g[c] + beta[c];
        if (outF) outF[(size_t)row * D_ + c] = val;
        if (outB) outB[(size_t)row * D_ + c] = f2b(val);
    }
}

// ---------------------------------------------------------------------------
extern "C" void kernel_launch(void* const* d_in, const int* in_sizes, int n_in,
                              void* d_out, int out_size, void* d_ws, size_t ws_size,
                              hipStream_t stream)
{
    const float* x   = (const float*)d_in[0];
    const float* Wq  = (const float*)d_in[2];
    const float* bq  = (const float*)d_in[3];
    const float* Wk  = (const float*)d_in[4];
    const float* bk  = (const float*)d_in[5];
    const float* Wv  = (const float*)d_in[6];
    const float* bv  = (const float*)d_in[7];
    const float* Wo  = (const float*)d_in[8];
    const float* bo  = (const float*)d_in[9];
    const float* phase_bias = (const float*)d_in[10];
    const float* freqs = (const float*)d_in[11];
    const float* W1  = (const float*)d_in[12];
    const float* b1  = (const float*)d_in[13];
    const float* W2  = (const float*)d_in[14];
    const float* b2  = (const float*)d_in[15];
    const float* g1  = (const float*)d_in[16];
    const float* be1 = (const float*)d_in[17];
    const float* g2  = (const float*)d_in[18];
    const float* be2 = (const float*)d_in[19];
    float* out = (float*)d_out;

    char* base = (char*)d_ws;
    const size_t MiB = 1024 * 1024;
    unsigned short* WqkvT = (unsigned short*)(base);             // [0,6)
    unsigned short* WoT   = (unsigned short*)(base + 6  * MiB);  // [6,8)
    unsigned short* W1T   = (unsigned short*)(base + 8  * MiB);  // [8,16)
    unsigned short* W2T   = (unsigned short*)(base + 16 * MiB);  // [16,24)
    float*          bqkv  = (float*)(base + 24 * MiB);           // [24,25)
    unsigned short* xb    = (unsigned short*)(base + 25 * MiB);  // [25,33)
    unsigned short* qkvb  = (unsigned short*)(base + 33 * MiB);  // [33,57)
    unsigned short* qpb   = (unsigned short*)(base + 57 * MiB);  // [57,73)
    unsigned short* kpb   = (unsigned short*)(base + 73 * MiB);  // [73,89)
    unsigned short* vtb   = (unsigned short*)(base + 89 * MiB);  // [89,97)
    float*          po    = (float*)(base + 89 * MiB);           // [89,121) 2 slices (vtb dead)
    unsigned short* aob   = xb;                                  // xb dead after QKV gemm
    unsigned short* x1b   = xb;                                  // aob dead after Wo gemm
    unsigned short* hb    = qkvb;                                // [33,65): qkvb+qpb dead
    float*          fo    = po;                                  // po dead after LN1

    dim3 blk(256);

    // prep
    conv_bf16_kernel<<<dim3(M_ * D_ / 1024), blk, 0, stream>>>(x, xb);
    wtrans_kernel<<<dim3(32, 32), blk, 0, stream>>>(Wq, WqkvT, D_, D_);
    wtrans_kernel<<<dim3(32, 32), blk, 0, stream>>>(Wk, WqkvT + (size_t)1024 * 1024, D_, D_);
    wtrans_kernel<<<dim3(32, 32), blk, 0, stream>>>(Wv, WqkvT + (size_t)2048 * 1024, D_, D_);
    wtrans_kernel<<<dim3(32, 32), blk, 0, stream>>>(Wo, WoT, D_, D_);
    wtrans_kernel<<<dim3(DFF_ / 32, D_ / 32), blk, 0, stream>>>(W1, W1T, D_, DFF_);
    wtrans_kernel<<<dim3(D_ / 32, DFF_ / 32), blk, 0, stream>>>(W2, W2T, DFF_, D_);
    bcat_kernel<<<dim3(12), blk, 0, stream>>>(bq, bk, bv, bqkv);

    // fused QKV projection -> bf16 qkvb
    gemm_bf16_kernel<<<dim3(3072 / 128, M_ / 128, 1), blk, 0, stream>>>(
        xb, WqkvT, bqkv, nullptr, qkvb, M_, D_, D_, 3072, 0);

    // PoPE + V transpose
    pope_kernel<<<dim3(B_ * H_ * S_ * HD_ / 256), blk, 0, stream>>>(
        qkvb, phase_bias, freqs, qpb, kpb);
    vtrans_kernel<<<dim3(S_ / 64, B_ * H_), blk, 0, stream>>>(qkvb, vtb);

    // Flash attention
    attn_mfma_kernel<<<dim3(8, B_ * H_, 2), dim3(512), 0, stream>>>(qpb, kpb, vtb, aob);

    // Output projection (split-K=2) + LN1 (bf16-only output)
    gemm_bf16_kernel<<<dim3(D_ / 128, M_ / 128, 2), blk, 0, stream>>>(
        aob, WoT, bo, po, nullptr, M_, D_ / 2, D_, D_, 0);
    ln_kernel<<<dim3(M_), blk, 0, stream>>>(
        po, po + (size_t)M_ * D_, x, nullptr, g1, be1, nullptr, x1b);

    // FFN
    gemm_bf16_kernel<<<dim3(DFF_ / 128, M_ / 128, 1), blk, 0, stream>>>(
        x1b, W1T, b1, nullptr, hb, M_, D_, D_, DFF_, 1);
    gemm_bf16_kernel<<<dim3(D_ / 128, M_ / 128, 2), blk, 0, stream>>>(
        hb, W2T, b2, fo, nullptr, M_, DFF_ / 2, DFF_, D_, 0);
    ln_kernel<<<dim3(M_), blk, 0, stream>>>(
        fo, fo + (size_t)M_ * D_, nullptr, x1b, g2, be2, out, nullptr);
}